// Round 4
// baseline (1426.005 us; speedup 1.0000x reference)
//
#include <hip/hip_runtime.h>
#include <hip/hip_cooperative_groups.h>
#include <math.h>

namespace cg = cooperative_groups;

#define EPS 1e-5f

typedef __attribute__((ext_vector_type(8))) short short8;
typedef __attribute__((ext_vector_type(4))) float f32x4;

__device__ __forceinline__ short f2bf(float f) {
    unsigned u = __float_as_uint(f);
    u += 0x7fffu + ((u >> 16) & 1u);
    return (short)(u >> 16);
}
__device__ __forceinline__ float bf2f(short s) {
    return __uint_as_float(((unsigned)(unsigned short)s) << 16);
}
__device__ __forceinline__ void async16(const void* g, void* l) {
    __builtin_amdgcn_global_load_lds(
        (const __attribute__((address_space(1))) unsigned*)g,
        (__attribute__((address_space(3))) unsigned*)l, 16, 0, 0);
}

// ---------------------------------------------------------------------------
__device__ __forceinline__ float block_reduce_sum_256(float v, float* red) {
    #pragma unroll
    for (int o = 32; o > 0; o >>= 1) v += __shfl_down(v, o, 64);
    __syncthreads();
    if ((threadIdx.x & 63) == 0) red[threadIdx.x >> 6] = v;
    __syncthreads();
    return red[0] + red[1] + red[2] + red[3];
}

// ---------------------------------------------------------------------------
__global__ __launch_bounds__(256) void film_kernel(
    const float* __restrict__ z, const float* __restrict__ fw,
    const float* __restrict__ fb, float* __restrict__ gb) {
    int bt = blockIdx.x;
    __shared__ float zs[32];
    if (threadIdx.x < 32) zs[threadIdx.x] = z[bt * 32 + threadIdx.x];
    __syncthreads();
    for (int j = threadIdx.x; j < 1024; j += 256) {
        float acc = fb[j];
        #pragma unroll
        for (int k = 0; k < 32; k++) acc = fmaf(zs[k], fw[k * 1024 + j], acc);
        gb[bt * 1024 + j] = acc;
    }
}

// ---------------------------------------------------------------------------
__global__ __launch_bounds__(256) void cvt_kernel(
    const float* __restrict__ src, short* __restrict__ dst, int n) {
    int i = blockIdx.x * 256 + threadIdx.x;
    if (i < n) dst[i] = f2bf(src[i]);
}

// x fp32 -> bf16, 8 elems per thread, coalesced
__global__ __launch_bounds__(256) void xcast_kernel(
    const float* __restrict__ x, short* __restrict__ xbf, int n8) {
    int i = blockIdx.x * 256 + threadIdx.x;
    if (i < n8) {
        float4 a = *(const float4*)(x + (size_t)i * 8);
        float4 b = *(const float4*)(x + (size_t)i * 8 + 4);
        short8 o = {f2bf(a.x), f2bf(a.y), f2bf(a.z), f2bf(a.w),
                    f2bf(b.x), f2bf(b.y), f2bf(b.z), f2bf(b.w)};
        *(short8*)(xbf + (size_t)i * 8) = o;
    }
}

// ---------------------------------------------------------------------------
// transpose + cast: src fp32 [L][K][N] -> dst bf16 [L][N][K]
__global__ __launch_bounds__(256) void tcast_kernel(
    const float* __restrict__ src, short* __restrict__ dst, int K, int N) {
    __shared__ float tile[32][33];
    src += (size_t)blockIdx.z * K * N;
    dst += (size_t)blockIdx.z * N * K;
    int n0 = blockIdx.x * 32, k0 = blockIdx.y * 32;
    int lx = threadIdx.x & 31, ly = threadIdx.x >> 5;
    #pragma unroll
    for (int i = 0; i < 32; i += 8)
        tile[ly + i][lx] = src[(size_t)(k0 + ly + i) * N + n0 + lx];
    __syncthreads();
    #pragma unroll
    for (int i = 0; i < 32; i += 8)
        dst[(size_t)(n0 + ly + i) * K + k0 + lx] = f2bf(tile[lx][ly + i]);
}

// ---------------------------------------------------------------------------
// Conv as GEMM, 128x128 tile, BK=64, XOR-swizzled LDS chunks.
// A = im2col from pre-cast xbf (bf16), B = conv weights bf16 [512][576].
__global__ __launch_bounds__(256) void conv_gemm(
    const short* __restrict__ xbf, const short* __restrict__ wbf,
    const float* __restrict__ cb, short* __restrict__ tok) {
    __shared__ short As[128 * 64];
    __shared__ short Bs[128 * 64];
    int tid = threadIdx.x;
    int n0 = blockIdx.x * 128, m0 = blockIdx.y * 128;
    int wave = tid >> 6, lane = tid & 63, quad = lane >> 4, l16 = lane & 15;
    int wm = wave & 1, wn = wave >> 1;

    // per-thread A staging constants (4 chunks per k-iter)
    int segA[4], tA[4];
    long long base0[4];
    #pragma unroll
    for (int e = 0; e < 4; e++) {
        int p = e * 256 + tid;
        int row = p >> 3;
        segA[e] = (p & 7) ^ (row & 7);
        int m = m0 + row;
        int bt = m >> 6, nn = m & 63;
        int b = bt >> 5, t = bt & 31;
        int hn = nn >> 3, wn2 = nn & 7;
        tA[e] = t;
        base0[e] = (((long long)(b * 32 + t - 2) * 3) << 12)
                   + (long long)(hn * 8) * 64 + wn2 * 8;
    }

    f32x4 acc[4][4];
    #pragma unroll
    for (int mt = 0; mt < 4; mt++)
        #pragma unroll
        for (int nt = 0; nt < 4; nt++) acc[mt][nt] = (f32x4){0.f, 0.f, 0.f, 0.f};

    for (int k0 = 0; k0 < 576; k0 += 64) {
        #pragma unroll
        for (int e = 0; e < 4; e++) {
            int p = e * 256 + tid;
            int n = p >> 3, seg = (p & 7) ^ (n & 7);
            async16(wbf + (size_t)(n0 + n) * 576 + k0 + seg * 8, Bs + p * 8);
        }
        #pragma unroll
        for (int e = 0; e < 4; e++) {
            int p = e * 256 + tid;
            int ks = (k0 >> 3) + segA[e];
            int ch = (ks >= 24) + (ks >= 48);
            int r = ks - ch * 24;
            int kt = r >> 3, ph = r & 7;
            short8 v8 = (short8){0, 0, 0, 0, 0, 0, 0, 0};
            if (tA[e] + kt >= 2)
                v8 = *(const short8*)(xbf + base0[e]
                        + ((long long)(kt * 3 + ch) << 12) + ph * 64);
            *(short8*)(As + p * 8) = v8;
        }
        __syncthreads();
        #pragma unroll
        for (int ksub = 0; ksub < 2; ksub++) {
            int ccb = ksub * 4 + quad;
            short8 af[4], bf[4];
            #pragma unroll
            for (int mt = 0; mt < 4; mt++) {
                int row = wm * 64 + mt * 16 + l16;
                af[mt] = *(const short8*)(As + (row * 8 + (ccb ^ (row & 7))) * 8);
            }
            #pragma unroll
            for (int nt = 0; nt < 4; nt++) {
                int row = wn * 64 + nt * 16 + l16;
                bf[nt] = *(const short8*)(Bs + (row * 8 + (ccb ^ (row & 7))) * 8);
            }
            #pragma unroll
            for (int mt = 0; mt < 4; mt++)
                #pragma unroll
                for (int nt = 0; nt < 4; nt++)
                    acc[mt][nt] = __builtin_amdgcn_mfma_f32_16x16x32_bf16(
                        af[mt], bf[nt], acc[mt][nt], 0, 0, 0);
        }
        __syncthreads();
    }
    #pragma unroll
    for (int mt = 0; mt < 4; mt++)
        #pragma unroll
        for (int nt = 0; nt < 4; nt++)
            #pragma unroll
            for (int reg = 0; reg < 4; reg++) {
                int m = m0 + wm * 64 + mt * 16 + quad * 4 + reg;
                int n = n0 + wn * 64 + nt * 16 + l16;
                tok[(size_t)m * 512 + n] = f2bf(acc[mt][nt][reg] + cb[n]);
            }
}

// ---------------------------------------------------------------------------
// tok_post: per (b,t): LN over 512 ch for each of 64 tokens + FiLM + mean -> h
__global__ __launch_bounds__(256) void tok_post(
    const short* __restrict__ tok, const float* __restrict__ tg,
    const float* __restrict__ tb, const float* __restrict__ gb,
    float* __restrict__ h) {
    __shared__ float mu_s[64], inv_s[64];
    __shared__ float red[4][512];
    int bt = blockIdx.x, tid = threadIdx.x;
    int wave = tid >> 6, lane = tid & 63;
    {
        int tokn = wave * 16 + (lane >> 2), part = lane & 3;
        const short* p = tok + (size_t)(bt * 64 + tokn) * 512 + part * 128;
        float s = 0.f, ss = 0.f;
        #pragma unroll
        for (int i = 0; i < 16; i++) {
            short8 v = *(const short8*)(p + i * 8);
            #pragma unroll
            for (int j = 0; j < 8; j++) {
                float f = bf2f(v[j]);
                s += f; ss += f * f;
            }
        }
        s += __shfl_xor(s, 1, 64); ss += __shfl_xor(ss, 1, 64);
        s += __shfl_xor(s, 2, 64); ss += __shfl_xor(ss, 2, 64);
        if (part == 0) {
            float mu = s * (1.f / 512.f);
            float var = ss * (1.f / 512.f) - mu * mu;
            mu_s[tokn] = mu;
            inv_s[tokn] = rsqrtf(var + EPS);
        }
    }
    __syncthreads();
    float hacc[8] = {0.f, 0.f, 0.f, 0.f, 0.f, 0.f, 0.f, 0.f};
    int c0 = lane * 8;
    for (int it = 0; it < 16; it++) {
        int n = it * 4 + wave;
        float mu = mu_s[n], inv = inv_s[n];
        short8 v = *(const short8*)(tok + (size_t)(bt * 64 + n) * 512 + c0);
        #pragma unroll
        for (int j = 0; j < 8; j++) hacc[j] += (bf2f(v[j]) - mu) * inv;
    }
    #pragma unroll
    for (int j = 0; j < 8; j++) red[wave][c0 + j] = hacc[j];
    __syncthreads();
    #pragma unroll
    for (int cc = 0; cc < 2; cc++) {
        int c = tid + cc * 256;
        float S = red[0][c] + red[1][c] + red[2][c] + red[3][c];
        float G  = 1.f + 0.5f * gb[bt * 1024 + c];
        float Be = 0.5f * gb[bt * 1024 + 512 + c];
        h[bt * 512 + c] = G * (tg[c] * (S * (1.f / 64.f)) + tb[c]) + Be;
    }
}

// ===========================================================================
// Cooperative transformer mega-kernel. Grid = 256 blocks x 256 threads.
// LDS: As 32KB @0, Bs 16KB @32768; attn overlays the same 48KB region.
// ===========================================================================
struct XArgs {
    float* h;            // [512][512] fp32 residual stream (rw)
    float* kqvf;         // [512][1536] fp32
    short* yv;           // [512][512] bf16
    short* mbuf;         // [512][2048] bf16
    const short *kqvT, *projT, *mlp1T, *mlp2T;
    const float *kqv_b, *proj_b, *mlp_b1, *mlp_b2;
    const float *ln1_g, *ln1_b, *ln2_g, *ln2_b;
    const float *rs_attn, *rs_mlp;
    const float *head_g, *head_b, *head_w, *head_bs;
    float* out;
};

// G1: LN(32 rows of h) inline -> As(full K=512, swizzled); B streamed.
// Tile 32m x 128n. mode 0: outf=acc+bias (fp32). mode 1: GELU -> outb bf16.
__device__ void gemm_lnA(
    const float* __restrict__ hsrc, const float* __restrict__ lng,
    const float* __restrict__ lnb, const short* __restrict__ Bw,
    const float* __restrict__ bias, int N, int nts, int bid, int mode,
    float* __restrict__ outf, short* __restrict__ outb,
    short* As, short* Bs, float* mu_s, float* inv_s) {
    if (bid >= 16 * nts) return;
    int mt = bid / nts, nt = bid - mt * nts;
    int m0 = mt * 32, n0 = nt * 128;
    int tid = threadIdx.x;
    // LN pass 1: stats
    {
        int row = tid >> 3, l8 = tid & 7;
        const float* hp = hsrc + (size_t)(m0 + row) * 512 + l8 * 64;
        float s = 0.f, ss = 0.f;
        #pragma unroll
        for (int i = 0; i < 16; i++) {
            float4 v = *(const float4*)(hp + i * 4);
            s += v.x + v.y + v.z + v.w;
            ss += v.x * v.x + v.y * v.y + v.z * v.z + v.w * v.w;
        }
        s += __shfl_xor(s, 1, 64); ss += __shfl_xor(ss, 1, 64);
        s += __shfl_xor(s, 2, 64); ss += __shfl_xor(ss, 2, 64);
        s += __shfl_xor(s, 4, 64); ss += __shfl_xor(ss, 4, 64);
        if (l8 == 0) {
            float mu = s * (1.f / 512.f);
            float var = ss * (1.f / 512.f) - mu * mu;
            mu_s[row] = mu;
            inv_s[row] = rsqrtf(var + EPS);
        }
    }
    __syncthreads();
    // LN pass 2: normalized bf16 -> As (swizzled chunks)
    for (int e = 0; e < 8; e++) {
        int lc = e * 256 + tid;
        int row = lc >> 6, cc = lc & 63;
        float mu = mu_s[row], inv = inv_s[row];
        const float* hp = hsrc + (size_t)(m0 + row) * 512 + cc * 8;
        float4 a = *(const float4*)hp, b = *(const float4*)(hp + 4);
        float4 g0 = *(const float4*)(lng + cc * 8), g1 = *(const float4*)(lng + cc * 8 + 4);
        float4 b0 = *(const float4*)(lnb + cc * 8), b1 = *(const float4*)(lnb + cc * 8 + 4);
        short8 o = {f2bf((a.x - mu) * inv * g0.x + b0.x),
                    f2bf((a.y - mu) * inv * g0.y + b0.y),
                    f2bf((a.z - mu) * inv * g0.z + b0.z),
                    f2bf((a.w - mu) * inv * g0.w + b0.w),
                    f2bf((b.x - mu) * inv * g1.x + b1.x),
                    f2bf((b.y - mu) * inv * g1.y + b1.y),
                    f2bf((b.z - mu) * inv * g1.z + b1.z),
                    f2bf((b.w - mu) * inv * g1.w + b1.w)};
        *(short8*)(As + (row * 64 + (cc ^ (row & 7))) * 8) = o;
    }
    __syncthreads();
    int wave = tid >> 6, lane = tid & 63, quad = lane >> 4, l16 = lane & 15;
    f32x4 acc[2][2];
    #pragma unroll
    for (int a2 = 0; a2 < 2; a2++)
        #pragma unroll
        for (int b2 = 0; b2 < 2; b2++) acc[a2][b2] = (f32x4){0.f, 0.f, 0.f, 0.f};
    for (int k0 = 0; k0 < 512; k0 += 64) {
        #pragma unroll
        for (int e = 0; e < 4; e++) {
            int p = e * 256 + tid;
            int n = p >> 3, seg = (p & 7) ^ (n & 7);
            async16(Bw + (size_t)(n0 + n) * 512 + k0 + seg * 8, Bs + p * 8);
        }
        __syncthreads();
        #pragma unroll
        for (int ksub = 0; ksub < 2; ksub++) {
            int ccb = ksub * 4 + quad;
            short8 af[2], bf[2];
            #pragma unroll
            for (int m2 = 0; m2 < 2; m2++) {
                int row = m2 * 16 + l16;
                int cc = (k0 >> 3) + ccb;
                af[m2] = *(const short8*)(As + (row * 64 + (cc ^ (row & 7))) * 8);
            }
            #pragma unroll
            for (int n2 = 0; n2 < 2; n2++) {
                int row = wave * 32 + n2 * 16 + l16;
                bf[n2] = *(const short8*)(Bs + (row * 8 + (ccb ^ (row & 7))) * 8);
            }
            #pragma unroll
            for (int m2 = 0; m2 < 2; m2++)
                #pragma unroll
                for (int n2 = 0; n2 < 2; n2++)
                    acc[m2][n2] = __builtin_amdgcn_mfma_f32_16x16x32_bf16(
                        af[m2], bf[n2], acc[m2][n2], 0, 0, 0);
        }
        __syncthreads();
    }
    #pragma unroll
    for (int m2 = 0; m2 < 2; m2++)
        #pragma unroll
        for (int n2 = 0; n2 < 2; n2++)
            #pragma unroll
            for (int reg = 0; reg < 4; reg++) {
                int m = m0 + m2 * 16 + quad * 4 + reg;
                int n = n0 + wave * 32 + n2 * 16 + l16;
                float v = acc[m2][n2][reg] + bias[n];
                if (mode == 1) {
                    v = 0.5f * v * (1.f + erff(v * 0.70710678118f));
                    outb[(size_t)m * N + n] = f2bf(v);
                } else {
                    outf[(size_t)m * N + n] = v;
                }
            }
}

// G2: A,B streamed bf16. Tile 32m x 64n, N=512 output. h += rs*(acc+bias).
__device__ void gemm_res(
    const short* __restrict__ Ag, const short* __restrict__ Bw,
    const float* __restrict__ bias, const float* __restrict__ rsPtr,
    float* __restrict__ hm, int K, int bid, short* AsI, short* Bs) {
    if (bid >= 128) return;
    int mt = bid >> 3, nt = bid & 7;
    int m0 = mt * 32, n0 = nt * 64;
    int tid = threadIdx.x;
    int wave = tid >> 6, lane = tid & 63, quad = lane >> 4, l16 = lane & 15;
    f32x4 acc[2];
    acc[0] = (f32x4){0.f, 0.f, 0.f, 0.f};
    acc[1] = (f32x4){0.f, 0.f, 0.f, 0.f};
    for (int k0 = 0; k0 < K; k0 += 64) {
        {
            int p = tid;
            int row = p >> 3, seg = (p & 7) ^ (row & 7);
            async16(Ag + (size_t)(m0 + row) * K + k0 + seg * 8, AsI + p * 8);
        }
        #pragma unroll
        for (int e = 0; e < 2; e++) {
            int p = e * 256 + tid;
            int n = p >> 3, seg = (p & 7) ^ (n & 7);
            async16(Bw + (size_t)(n0 + n) * K + k0 + seg * 8, Bs + p * 8);
        }
        __syncthreads();
        #pragma unroll
        for (int ksub = 0; ksub < 2; ksub++) {
            int ccb = ksub * 4 + quad;
            short8 bf;
            {
                int row = wave * 16 + l16;
                bf = *(const short8*)(Bs + (row * 8 + (ccb ^ (row & 7))) * 8);
            }
            #pragma unroll
            for (int m2 = 0; m2 < 2; m2++) {
                int row = m2 * 16 + l16;
                short8 af = *(const short8*)(AsI + (row * 8 + (ccb ^ (row & 7))) * 8);
                acc[m2] = __builtin_amdgcn_mfma_f32_16x16x32_bf16(af, bf, acc[m2], 0, 0, 0);
            }
        }
        __syncthreads();
    }
    float rsv = *rsPtr;
    #pragma unroll
    for (int m2 = 0; m2 < 2; m2++)
        #pragma unroll
        for (int reg = 0; reg < 4; reg++) {
            int m = m0 + m2 * 16 + quad * 4 + reg;
            int n = n0 + wave * 16 + l16;
            size_t off = (size_t)m * 512 + n;
            hm[off] = hm[off] + rsv * (acc[m2][reg] + bias[n]);
        }
}

// attention stage: 128 blocks = (b, head). fp32 in (kqvf), bf16 out (yv).
__device__ void attn_stage(const float* __restrict__ kqv, short* __restrict__ yv,
                           int bid, char* smraw) {
    if (bid >= 128) return;
    float (*qs)[64] = (float(*)[64])(smraw);
    float (*ks)[64] = (float(*)[64])(smraw + 8192);
    float (*vs)[64] = (float(*)[64])(smraw + 16384);
    float (*qr)[64] = (float(*)[64])(smraw + 24576);
    float (*kr)[64] = (float(*)[64])(smraw + 32768);
    float (*att)[32] = (float(*)[32])(smraw + 40960);
    int b = bid >> 3, hh = bid & 7;
    int tid = threadIdx.x;
    for (int idx = tid; idx < 2048; idx += 256) {
        int t = idx >> 6, d = idx & 63;
        const float* base = kqv + (size_t)(b * 32 + t) * 1536 + hh * 64 + d;
        ks[t][d] = base[0];
        qs[t][d] = base[512];
        vs[t][d] = base[1024];
    }
    __syncthreads();
    const float lnb = logf(10000.f) / 32.f;
    for (int idx = tid; idx < 2048; idx += 256) {
        int t = idx >> 6, d = idx & 63;
        int j = d & 31;
        float ang = (float)t * expf(-(float)j * lnb);
        float sv = sinf(ang), cv = cosf(ang);
        float qv = qs[t][d], kv = ks[t][d];
        float qo = qs[t][d ^ 32], ko = ks[t][d ^ 32];
        float rq = (d < 32) ? -qo : qo;
        float rk = (d < 32) ? -ko : ko;
        qr[t][d] = qv * cv + rq * sv;
        kr[t][d] = kv * cv + rk * sv;
    }
    __syncthreads();
    #pragma unroll
    for (int l = 0; l < 4; l++) {
        int idx = l * 256 + tid;
        int qt = idx >> 5, kt2 = idx & 31;
        float s;
        if (kt2 > qt) {
            s = -1e30f;
        } else {
            float a = 0.f;
            #pragma unroll
            for (int d = 0; d < 64; d++) a = fmaf(qr[qt][d], kr[kt2][d], a);
            s = a * 0.125f;
        }
        att[qt][kt2] = s;
    }
    __syncthreads();
    if (tid < 32) {
        float m = -1e30f;
        #pragma unroll
        for (int k = 0; k < 32; k++) m = fmaxf(m, att[tid][k]);
        float sum = 0.f;
        #pragma unroll
        for (int k = 0; k < 32; k++) {
            float e = expf(att[tid][k] - m);
            att[tid][k] = e;
            sum += e;
        }
        float inv = 1.f / sum;
        #pragma unroll
        for (int k = 0; k < 32; k++) att[tid][k] *= inv;
    }
    __syncthreads();
    for (int idx = tid; idx < 2048; idx += 256) {
        int t = idx >> 6, d = idx & 63;
        float a = 0.f;
        #pragma unroll
        for (int k = 0; k < 32; k++) a = fmaf(att[t][k], vs[k][d], a);
        yv[(size_t)(b * 32 + t) * 512 + hh * 64 + d] = f2bf(a);
    }
}

__global__ __launch_bounds__(256) void xformer(XArgs P) {
    cg::grid_group gg = cg::this_grid();
    __shared__ char smraw[49152] __attribute__((aligned(16)));
    __shared__ float mu_s[32], inv_s[32], red8[8];
    short* As = (short*)smraw;
    short* Bs = (short*)(smraw + 32768);
    int bid = blockIdx.x;
    int tid = threadIdx.x;

    for (int i = 0; i < 6; i++) {
        gemm_lnA(P.h, P.ln1_g + i * 512, P.ln1_b + i * 512,
                 P.kqvT + (size_t)i * 1536 * 512, P.kqv_b + i * 1536,
                 1536, 12, bid, 0, P.kqvf, nullptr, As, Bs, mu_s, inv_s);
        gg.sync();
        attn_stage(P.kqvf, P.yv, bid, smraw);
        gg.sync();
        gemm_res(P.yv, P.projT + (size_t)i * 512 * 512, P.proj_b + i * 512,
                 P.rs_attn + i, P.h, 512, bid, As, Bs);
        gg.sync();
        gemm_lnA(P.h, P.ln2_g + i * 512, P.ln2_b + i * 512,
                 P.mlp1T + (size_t)i * 2048 * 512, P.mlp_b1 + i * 2048,
                 2048, 16, bid, 1, nullptr, P.mbuf, As, Bs, mu_s, inv_s);
        gg.sync();
        gemm_res(P.mbuf, P.mlp2T + (size_t)i * 512 * 2048, P.mlp_b2 + i * 512,
                 P.rs_mlp + i, P.h, 2048, bid, As, Bs);
        gg.sync();
    }
    // head: 2 tokens per block
    #pragma unroll
    for (int e = 0; e < 2; e++) {
        int token = bid * 2 + e;
        float v0 = P.h[(size_t)token * 512 + tid];
        float v1 = P.h[(size_t)token * 512 + tid + 256];
        float s  = block_reduce_sum_256(v0 + v1, red8);
        float ss = block_reduce_sum_256(v0 * v0 + v1 * v1, red8);
        float mu = s * (1.f / 512.f);
        float var = ss * (1.f / 512.f) - mu * mu;
        float inv = rsqrtf(var + EPS);
        float n0 = (v0 - mu) * inv * P.head_g[tid] + P.head_b[tid];
        float n1 = (v1 - mu) * inv * P.head_g[tid + 256] + P.head_b[tid + 256];
        float dot = block_reduce_sum_256(n0 * P.head_w[tid] + n1 * P.head_w[tid + 256], red8);
        if (tid == 0) P.out[token] = dot + P.head_bs[0];
    }
}

// ---------------------------------------------------------------------------
extern "C" void kernel_launch(void* const* d_in, const int* in_sizes, int n_in,
                              void* d_out, int out_size, void* d_ws, size_t ws_size,
                              hipStream_t stream) {
    const float* x       = (const float*)d_in[0];
    const float* z       = (const float*)d_in[1];
    const float* conv_w  = (const float*)d_in[2];
    const float* conv_b  = (const float*)d_in[3];
    const float* tok_g   = (const float*)d_in[4];
    const float* tok_b   = (const float*)d_in[5];
    const float* film_w  = (const float*)d_in[6];
    const float* film_b  = (const float*)d_in[7];
    const float* ln1_g   = (const float*)d_in[8];
    const float* ln1_b   = (const float*)d_in[9];
    const float* kqv_w   = (const float*)d_in[10];
    const float* kqv_b   = (const float*)d_in[11];
    const float* proj_w  = (const float*)d_in[12];
    const float* proj_b  = (const float*)d_in[13];
    const float* ln2_g   = (const float*)d_in[14];
    const float* ln2_b   = (const float*)d_in[15];
    const float* mlp_w1  = (const float*)d_in[16];
    const float* mlp_b1  = (const float*)d_in[17];
    const float* mlp_w2  = (const float*)d_in[18];
    const float* mlp_b2  = (const float*)d_in[19];
    const float* rs_attn = (const float*)d_in[20];
    const float* rs_mlp  = (const float*)d_in[21];
    const float* head_g  = (const float*)d_in[22];
    const float* head_b  = (const float*)d_in[23];
    const float* head_w  = (const float*)d_in[24];
    const float* head_bs = (const float*)d_in[25];
    float* out = (float*)d_out;

    float* ws = (float*)d_ws;
    float* gb   = ws;                  // 524288 f
    float* h    = gb + 524288;         // 262144 f
    float* kqvf = h + 262144;          // 786432 f
    short* sb = (short*)(kqvf + 786432);
    short* wbf   = sb;                 // 294912
    short* kqvT  = wbf   + 294912;     // 4718592
    short* projT = kqvT  + 4718592;    // 1572864
    short* mlp1T = projT + 1572864;    // 6291456
    short* mlp2T = mlp1T + 6291456;    // 6291456
    short* tokb  = mlp2T + 6291456;    // 16777216
    short* yvb   = tokb  + 16777216;   // 262144
    short* mbuf  = yvb   + 262144;     // 1048576
    short* xbf   = mbuf  + 1048576;    // 6291456
    // totals: 6.3 MB (fp32) + ~87 MB (bf16)

    film_kernel<<<512, 256, 0, stream>>>(z, film_w, film_b, gb);
    cvt_kernel<<<1152, 256, 0, stream>>>(conv_w, wbf, 294912);
    xcast_kernel<<<3072, 256, 0, stream>>>(x, xbf, 786432);
    tcast_kernel<<<dim3(48, 16, 6), 256, 0, stream>>>(kqv_w, kqvT, 512, 1536);
    tcast_kernel<<<dim3(16, 16, 6), 256, 0, stream>>>(proj_w, projT, 512, 512);
    tcast_kernel<<<dim3(64, 16, 6), 256, 0, stream>>>(mlp_w1, mlp1T, 512, 2048);
    tcast_kernel<<<dim3(16, 64, 6), 256, 0, stream>>>(mlp_w2, mlp2T, 2048, 512);

    conv_gemm<<<dim3(4, 256), 256, 0, stream>>>(xbf, wbf, conv_b, tokb);
    tok_post<<<512, 256, 0, stream>>>(tokb, tok_g, tok_b, gb, h);

    XArgs xa;
    xa.h = h; xa.kqvf = kqvf; xa.yv = yvb; xa.mbuf = mbuf;
    xa.kqvT = kqvT; xa.projT = projT; xa.mlp1T = mlp1T; xa.mlp2T = mlp2T;
    xa.kqv_b = kqv_b; xa.proj_b = proj_b; xa.mlp_b1 = mlp_b1; xa.mlp_b2 = mlp_b2;
    xa.ln1_g = ln1_g; xa.ln1_b = ln1_b; xa.ln2_g = ln2_g; xa.ln2_b = ln2_b;
    xa.rs_attn = rs_attn; xa.rs_mlp = rs_mlp;
    xa.head_g = head_g; xa.head_b = head_b; xa.head_w = head_w; xa.head_bs = head_bs;
    xa.out = out;
    void* kargs[] = {(void*)&xa};
    hipLaunchCooperativeKernel((const void*)xformer, dim3(256), dim3(256),
                               kargs, 0, stream);
}

// Round 5
// 580.604 us; speedup vs baseline: 2.4561x; 2.4561x over previous
//
#include <hip/hip_runtime.h>
#include <math.h>

#define EPS 1e-5f

typedef __attribute__((ext_vector_type(8))) short short8;
typedef __attribute__((ext_vector_type(4))) float f32x4;

__device__ __forceinline__ short f2bf(float f) {
    unsigned u = __float_as_uint(f);
    u += 0x7fffu + ((u >> 16) & 1u);
    return (short)(u >> 16);
}
__device__ __forceinline__ float bf2f(short s) {
    return __uint_as_float(((unsigned)(unsigned short)s) << 16);
}
__device__ __forceinline__ void async16(const void* g, void* l) {
    __builtin_amdgcn_global_load_lds(
        (const __attribute__((address_space(1))) unsigned*)g,
        (__attribute__((address_space(3))) unsigned*)l, 16, 0, 0);
}

// ---------------------------------------------------------------------------
__device__ __forceinline__ float block_reduce_sum_256(float v, float* red) {
    #pragma unroll
    for (int o = 32; o > 0; o >>= 1) v += __shfl_down(v, o, 64);
    __syncthreads();
    if ((threadIdx.x & 63) == 0) red[threadIdx.x >> 6] = v;
    __syncthreads();
    return red[0] + red[1] + red[2] + red[3];
}

// ---------------------------------------------------------------------------
__global__ __launch_bounds__(256) void film_kernel(
    const float* __restrict__ z, const float* __restrict__ fw,
    const float* __restrict__ fb, float* __restrict__ gb) {
    int bt = blockIdx.x;
    __shared__ float zs[32];
    if (threadIdx.x < 32) zs[threadIdx.x] = z[bt * 32 + threadIdx.x];
    __syncthreads();
    for (int j = threadIdx.x; j < 1024; j += 256) {
        float acc = fb[j];
        #pragma unroll
        for (int k = 0; k < 32; k++) acc = fmaf(zs[k], fw[k * 1024 + j], acc);
        gb[bt * 1024 + j] = acc;
    }
}

// ---------------------------------------------------------------------------
__global__ __launch_bounds__(256) void cvt_kernel(
    const float* __restrict__ src, short* __restrict__ dst, int n) {
    int i = blockIdx.x * 256 + threadIdx.x;
    if (i < n) dst[i] = f2bf(src[i]);
}

__global__ __launch_bounds__(256) void xcast_kernel(
    const float* __restrict__ x, short* __restrict__ xbf, int n8) {
    int i = blockIdx.x * 256 + threadIdx.x;
    if (i < n8) {
        float4 a = *(const float4*)(x + (size_t)i * 8);
        float4 b = *(const float4*)(x + (size_t)i * 8 + 4);
        short8 o = {f2bf(a.x), f2bf(a.y), f2bf(a.z), f2bf(a.w),
                    f2bf(b.x), f2bf(b.y), f2bf(b.z), f2bf(b.w)};
        *(short8*)(xbf + (size_t)i * 8) = o;
    }
}

// ---------------------------------------------------------------------------
// transpose + cast: src fp32 [L][K][N] -> dst bf16 [L][N][K]
__global__ __launch_bounds__(256) void tcast_kernel(
    const float* __restrict__ src, short* __restrict__ dst, int K, int N) {
    __shared__ float tile[32][33];
    src += (size_t)blockIdx.z * K * N;
    dst += (size_t)blockIdx.z * N * K;
    int n0 = blockIdx.x * 32, k0 = blockIdx.y * 32;
    int lx = threadIdx.x & 31, ly = threadIdx.x >> 5;
    #pragma unroll
    for (int i = 0; i < 32; i += 8)
        tile[ly + i][lx] = src[(size_t)(k0 + ly + i) * N + n0 + lx];
    __syncthreads();
    #pragma unroll
    for (int i = 0; i < 32; i += 8)
        dst[(size_t)(n0 + ly + i) * K + k0 + lx] = f2bf(tile[lx][ly + i]);
}

// ---------------------------------------------------------------------------
// Conv as GEMM, 128x128 tile, BK=64, XOR-swizzled LDS chunks (W=8).
__global__ __launch_bounds__(256) void conv_gemm(
    const short* __restrict__ xbf, const short* __restrict__ wbf,
    const float* __restrict__ cb, short* __restrict__ tok) {
    __shared__ short As[128 * 64];
    __shared__ short Bs[128 * 64];
    int tid = threadIdx.x;
    int n0 = blockIdx.x * 128, m0 = blockIdx.y * 128;
    int wave = tid >> 6, lane = tid & 63, quad = lane >> 4, l16 = lane & 15;
    int wm = wave & 1, wn = wave >> 1;

    int segA[4], tA[4];
    long long base0[4];
    #pragma unroll
    for (int e = 0; e < 4; e++) {
        int p = e * 256 + tid;
        int row = p >> 3;
        segA[e] = (p & 7) ^ (row & 7);
        int m = m0 + row;
        int bt = m >> 6, nn = m & 63;
        int b = bt >> 5, t = bt & 31;
        int hn = nn >> 3, wn2 = nn & 7;
        tA[e] = t;
        base0[e] = (((long long)(b * 32 + t - 2) * 3) << 12)
                   + (long long)(hn * 8) * 64 + wn2 * 8;
    }

    f32x4 acc[4][4];
    #pragma unroll
    for (int mt = 0; mt < 4; mt++)
        #pragma unroll
        for (int nt = 0; nt < 4; nt++) acc[mt][nt] = (f32x4){0.f, 0.f, 0.f, 0.f};

    for (int k0 = 0; k0 < 576; k0 += 64) {
        #pragma unroll
        for (int e = 0; e < 4; e++) {
            int p = e * 256 + tid;
            int n = p >> 3, seg = (p & 7) ^ (n & 7);
            async16(wbf + (size_t)(n0 + n) * 576 + k0 + seg * 8, Bs + p * 8);
        }
        #pragma unroll
        for (int e = 0; e < 4; e++) {
            int p = e * 256 + tid;
            int ks = (k0 >> 3) + segA[e];
            int ch = (ks >= 24) + (ks >= 48);
            int r = ks - ch * 24;
            int kt = r >> 3, ph = r & 7;
            short8 v8 = (short8){0, 0, 0, 0, 0, 0, 0, 0};
            if (tA[e] + kt >= 2)
                v8 = *(const short8*)(xbf + base0[e]
                        + ((long long)(kt * 3 + ch) << 12) + ph * 64);
            *(short8*)(As + p * 8) = v8;
        }
        __syncthreads();
        #pragma unroll
        for (int ksub = 0; ksub < 2; ksub++) {
            int ccb = ksub * 4 + quad;
            short8 af[4], bf[4];
            #pragma unroll
            for (int mt = 0; mt < 4; mt++) {
                int row = wm * 64 + mt * 16 + l16;
                af[mt] = *(const short8*)(As + (row * 8 + (ccb ^ (row & 7))) * 8);
            }
            #pragma unroll
            for (int nt = 0; nt < 4; nt++) {
                int row = wn * 64 + nt * 16 + l16;
                bf[nt] = *(const short8*)(Bs + (row * 8 + (ccb ^ (row & 7))) * 8);
            }
            #pragma unroll
            for (int mt = 0; mt < 4; mt++)
                #pragma unroll
                for (int nt = 0; nt < 4; nt++)
                    acc[mt][nt] = __builtin_amdgcn_mfma_f32_16x16x32_bf16(
                        af[mt], bf[nt], acc[mt][nt], 0, 0, 0);
        }
        __syncthreads();
    }
    #pragma unroll
    for (int mt = 0; mt < 4; mt++)
        #pragma unroll
        for (int nt = 0; nt < 4; nt++)
            #pragma unroll
            for (int reg = 0; reg < 4; reg++) {
                int m = m0 + wm * 64 + mt * 16 + quad * 4 + reg;
                int n = n0 + wn * 64 + nt * 16 + l16;
                tok[(size_t)m * 512 + n] = f2bf(acc[mt][nt][reg] + cb[n]);
            }
}

// ---------------------------------------------------------------------------
// tok_post: per (b,t): LN over 512 ch for each of 64 tokens + FiLM + mean -> h
__global__ __launch_bounds__(256) void tok_post(
    const short* __restrict__ tok, const float* __restrict__ tg,
    const float* __restrict__ tb, const float* __restrict__ gb,
    float* __restrict__ h) {
    __shared__ float mu_s[64], inv_s[64];
    __shared__ float red[4][512];
    int bt = blockIdx.x, tid = threadIdx.x;
    int wave = tid >> 6, lane = tid & 63;
    {
        int tokn = wave * 16 + (lane >> 2), part = lane & 3;
        const short* p = tok + (size_t)(bt * 64 + tokn) * 512 + part * 128;
        float s = 0.f, ss = 0.f;
        #pragma unroll
        for (int i = 0; i < 16; i++) {
            short8 v = *(const short8*)(p + i * 8);
            #pragma unroll
            for (int j = 0; j < 8; j++) {
                float f = bf2f(v[j]);
                s += f; ss += f * f;
            }
        }
        s += __shfl_xor(s, 1, 64); ss += __shfl_xor(ss, 1, 64);
        s += __shfl_xor(s, 2, 64); ss += __shfl_xor(ss, 2, 64);
        if (part == 0) {
            float mu = s * (1.f / 512.f);
            float var = ss * (1.f / 512.f) - mu * mu;
            mu_s[tokn] = mu;
            inv_s[tokn] = rsqrtf(var + EPS);
        }
    }
    __syncthreads();
    float hacc[8] = {0.f, 0.f, 0.f, 0.f, 0.f, 0.f, 0.f, 0.f};
    int c0 = lane * 8;
    for (int it = 0; it < 16; it++) {
        int n = it * 4 + wave;
        float mu = mu_s[n], inv = inv_s[n];
        short8 v = *(const short8*)(tok + (size_t)(bt * 64 + n) * 512 + c0);
        #pragma unroll
        for (int j = 0; j < 8; j++) hacc[j] += (bf2f(v[j]) - mu) * inv;
    }
    #pragma unroll
    for (int j = 0; j < 8; j++) red[wave][c0 + j] = hacc[j];
    __syncthreads();
    #pragma unroll
    for (int cc = 0; cc < 2; cc++) {
        int c = tid + cc * 256;
        float S = red[0][c] + red[1][c] + red[2][c] + red[3][c];
        float G  = 1.f + 0.5f * gb[bt * 1024 + c];
        float Be = 0.5f * gb[bt * 1024 + 512 + c];
        h[bt * 512 + c] = G * (tg[c] * (S * (1.f / 64.f)) + tb[c]) + Be;
    }
}

// ---------------------------------------------------------------------------
// gemm_ln: LN(h 32-row tile) -> As (full K=512, swizzled W=64), B streamed
// bf16 [N][512] with BK=128 (swizzled W=16). Tile 32m x 128n.
// mode 0: outf = acc + bias (fp32). mode 1: GELU -> outb (bf16).
__global__ __launch_bounds__(256) void gemm_ln(
    const float* __restrict__ hsrc, const float* __restrict__ lng,
    const float* __restrict__ lnb, const short* __restrict__ Bw,
    const float* __restrict__ bias, int N, int mode,
    float* __restrict__ outf, short* __restrict__ outb) {
    __shared__ short As[32 * 512];     // 32 KB, full K, swizzled chunks (W=64)
    __shared__ short Bs[128 * 128];    // 32 KB, BK=128, swizzled (W=16)
    __shared__ float mu_s[32], inv_s[32];
    int tid = threadIdx.x;
    int m0 = blockIdx.y * 32, n0 = blockIdx.x * 128;
    // LN pass 1: stats (8 lanes per row)
    {
        int row = tid >> 3, l8 = tid & 7;
        const float* hp = hsrc + (size_t)(m0 + row) * 512 + l8 * 64;
        float s = 0.f, ss = 0.f;
        #pragma unroll
        for (int i = 0; i < 16; i++) {
            float4 v = *(const float4*)(hp + i * 4);
            s += v.x + v.y + v.z + v.w;
            ss += v.x * v.x + v.y * v.y + v.z * v.z + v.w * v.w;
        }
        s += __shfl_xor(s, 1, 64); ss += __shfl_xor(ss, 1, 64);
        s += __shfl_xor(s, 2, 64); ss += __shfl_xor(ss, 2, 64);
        s += __shfl_xor(s, 4, 64); ss += __shfl_xor(ss, 4, 64);
        if (l8 == 0) {
            float mu = s * (1.f / 512.f);
            float var = ss * (1.f / 512.f) - mu * mu;
            mu_s[row] = mu;
            inv_s[row] = rsqrtf(var + EPS);
        }
    }
    __syncthreads();
    // LN pass 2: normalized bf16 -> As (chunk cc swizzled by row&7)
    #pragma unroll
    for (int e = 0; e < 8; e++) {
        int lc = e * 256 + tid;
        int row = lc >> 6, cc = lc & 63;
        float mu = mu_s[row], inv = inv_s[row];
        const float* hp = hsrc + (size_t)(m0 + row) * 512 + cc * 8;
        float4 a = *(const float4*)hp, b = *(const float4*)(hp + 4);
        float4 g0 = *(const float4*)(lng + cc * 8), g1 = *(const float4*)(lng + cc * 8 + 4);
        float4 b0 = *(const float4*)(lnb + cc * 8), b1 = *(const float4*)(lnb + cc * 8 + 4);
        short8 o = {f2bf((a.x - mu) * inv * g0.x + b0.x),
                    f2bf((a.y - mu) * inv * g0.y + b0.y),
                    f2bf((a.z - mu) * inv * g0.z + b0.z),
                    f2bf((a.w - mu) * inv * g0.w + b0.w),
                    f2bf((b.x - mu) * inv * g1.x + b1.x),
                    f2bf((b.y - mu) * inv * g1.y + b1.y),
                    f2bf((b.z - mu) * inv * g1.z + b1.z),
                    f2bf((b.w - mu) * inv * g1.w + b1.w)};
        *(short8*)(As + (row * 64 + (cc ^ (row & 7))) * 8) = o;
    }
    __syncthreads();
    int wave = tid >> 6, lane = tid & 63, quad = lane >> 4, l16 = lane & 15;
    f32x4 acc[2][2];
    #pragma unroll
    for (int a2 = 0; a2 < 2; a2++)
        #pragma unroll
        for (int b2 = 0; b2 < 2; b2++) acc[a2][b2] = (f32x4){0.f, 0.f, 0.f, 0.f};
    for (int k0 = 0; k0 < 512; k0 += 128) {
        #pragma unroll
        for (int e = 0; e < 8; e++) {
            int p = e * 256 + tid;
            int row = p >> 4, seg = (p & 15) ^ (row & 15);
            async16(Bw + (size_t)(n0 + row) * 512 + k0 + seg * 8, Bs + p * 8);
        }
        __syncthreads();
        #pragma unroll
        for (int ksub = 0; ksub < 4; ksub++) {
            int ccb = ksub * 4 + quad;
            short8 af[2], bf[2];
            #pragma unroll
            for (int m2 = 0; m2 < 2; m2++) {
                int row = m2 * 16 + l16;
                int cc = (k0 >> 3) + ccb;
                af[m2] = *(const short8*)(As + (row * 64 + (cc ^ (row & 7))) * 8);
            }
            #pragma unroll
            for (int n2 = 0; n2 < 2; n2++) {
                int row = wave * 32 + n2 * 16 + l16;
                bf[n2] = *(const short8*)(Bs + (row * 16 + (ccb ^ (row & 15))) * 8);
            }
            #pragma unroll
            for (int m2 = 0; m2 < 2; m2++)
                #pragma unroll
                for (int n2 = 0; n2 < 2; n2++)
                    acc[m2][n2] = __builtin_amdgcn_mfma_f32_16x16x32_bf16(
                        af[m2], bf[n2], acc[m2][n2], 0, 0, 0);
        }
        __syncthreads();
    }
    #pragma unroll
    for (int m2 = 0; m2 < 2; m2++)
        #pragma unroll
        for (int n2 = 0; n2 < 2; n2++)
            #pragma unroll
            for (int reg = 0; reg < 4; reg++) {
                int m = m0 + m2 * 16 + quad * 4 + reg;
                int n = n0 + wave * 32 + n2 * 16 + l16;
                float v = acc[m2][n2][reg] + bias[n];
                if (mode == 1) {
                    v = 0.5f * v * (1.f + erff(v * 0.70710678118f));
                    outb[(size_t)m * N + n] = f2bf(v);
                } else {
                    outf[(size_t)m * N + n] = v;
                }
            }
}

// ---------------------------------------------------------------------------
// gemm_res: A[M][K] bf16, B[N][K] bf16, BK=128 (swizzled W=16).
// Tile 32m x 64n, output N=512: h[m][n] += rs * (acc + bias).
__global__ __launch_bounds__(256) void gemm_res(
    const short* __restrict__ Ag, const short* __restrict__ Bw,
    const float* __restrict__ bias, const float* __restrict__ rsPtr,
    float* __restrict__ hm, int K) {
    __shared__ short As[32 * 128];     // 8 KB
    __shared__ short Bs[64 * 128];     // 16 KB
    int tid = threadIdx.x;
    int m0 = blockIdx.y * 32, n0 = blockIdx.x * 64;
    int wave = tid >> 6, lane = tid & 63, quad = lane >> 4, l16 = lane & 15;
    f32x4 acc[2];
    acc[0] = (f32x4){0.f, 0.f, 0.f, 0.f};
    acc[1] = (f32x4){0.f, 0.f, 0.f, 0.f};
    for (int k0 = 0; k0 < K; k0 += 128) {
        #pragma unroll
        for (int e = 0; e < 2; e++) {
            int p = e * 256 + tid;
            int row = p >> 4, seg = (p & 15) ^ (row & 15);
            async16(Ag + (size_t)(m0 + row) * K + k0 + seg * 8, As + p * 8);
        }
        #pragma unroll
        for (int e = 0; e < 4; e++) {
            int p = e * 256 + tid;
            int row = p >> 4, seg = (p & 15) ^ (row & 15);
            async16(Bw + (size_t)(n0 + row) * K + k0 + seg * 8, Bs + p * 8);
        }
        __syncthreads();
        #pragma unroll
        for (int ksub = 0; ksub < 4; ksub++) {
            int ccb = ksub * 4 + quad;
            short8 bf;
            {
                int row = wave * 16 + l16;
                bf = *(const short8*)(Bs + (row * 16 + (ccb ^ (row & 15))) * 8);
            }
            #pragma unroll
            for (int m2 = 0; m2 < 2; m2++) {
                int row = m2 * 16 + l16;
                short8 af = *(const short8*)(As + (row * 16 + (ccb ^ (row & 15))) * 8);
                acc[m2] = __builtin_amdgcn_mfma_f32_16x16x32_bf16(af, bf, acc[m2], 0, 0, 0);
            }
        }
        __syncthreads();
    }
    float rsv = *rsPtr;
    #pragma unroll
    for (int m2 = 0; m2 < 2; m2++)
        #pragma unroll
        for (int reg = 0; reg < 4; reg++) {
            int m = m0 + m2 * 16 + quad * 4 + reg;
            int n = n0 + wave * 16 + l16;
            size_t off = (size_t)m * 512 + n;
            hm[off] = hm[off] + rsv * (acc[m2][reg] + bias[n]);
        }
}

// ---------------------------------------------------------------------------
// Attention for one (b, head). T=32, DH=64, causal, RoPE. fp32 in, bf16 out.
__global__ __launch_bounds__(256) void attn_kernel(
    const float* __restrict__ kqv, short* __restrict__ yv) {
    __shared__ float qs[32][64], ks[32][64], vs[32][64];
    __shared__ float qr[32][64], kr[32][64];
    __shared__ float att[32][32];
    int blk = blockIdx.x;
    int b = blk >> 3, hh = blk & 7;
    int tid = threadIdx.x;

    for (int idx = tid; idx < 2048; idx += 256) {
        int t = idx >> 6, d = idx & 63;
        const float* base = kqv + (size_t)(b * 32 + t) * 1536 + hh * 64 + d;
        ks[t][d] = base[0];
        qs[t][d] = base[512];
        vs[t][d] = base[1024];
    }
    __syncthreads();
    const float lnb = logf(10000.f) / 32.f;
    for (int idx = tid; idx < 2048; idx += 256) {
        int t = idx >> 6, d = idx & 63;
        int j = d & 31;
        float ang = (float)t * expf(-(float)j * lnb);
        float sv = sinf(ang), cv = cosf(ang);
        float qv = qs[t][d], kv = ks[t][d];
        float qo = qs[t][d ^ 32], ko = ks[t][d ^ 32];
        float rq = (d < 32) ? -qo : qo;
        float rk = (d < 32) ? -ko : ko;
        qr[t][d] = qv * cv + rq * sv;
        kr[t][d] = kv * cv + rk * sv;
    }
    __syncthreads();
    #pragma unroll
    for (int l = 0; l < 4; l++) {
        int idx = l * 256 + tid;
        int qt = idx >> 5, kt2 = idx & 31;
        float s;
        if (kt2 > qt) {
            s = -1e30f;
        } else {
            float a = 0.f;
            #pragma unroll
            for (int d = 0; d < 64; d++) a = fmaf(qr[qt][d], kr[kt2][d], a);
            s = a * 0.125f;
        }
        att[qt][kt2] = s;
    }
    __syncthreads();
    if (tid < 32) {
        float m = -1e30f;
        #pragma unroll
        for (int k = 0; k < 32; k++) m = fmaxf(m, att[tid][k]);
        float sum = 0.f;
        #pragma unroll
        for (int k = 0; k < 32; k++) {
            float e = expf(att[tid][k] - m);
            att[tid][k] = e;
            sum += e;
        }
        float inv = 1.f / sum;
        #pragma unroll
        for (int k = 0; k < 32; k++) att[tid][k] *= inv;
    }
    __syncthreads();
    for (int idx = tid; idx < 2048; idx += 256) {
        int t = idx >> 6, d = idx & 63;
        float a = 0.f;
        #pragma unroll
        for (int k = 0; k < 32; k++) a = fmaf(att[t][k], vs[k][d], a);
        yv[(size_t)(b * 32 + t) * 512 + hh * 64 + d] = f2bf(a);
    }
}

// ---------------------------------------------------------------------------
__global__ __launch_bounds__(256) void head_kernel(
    const float* __restrict__ h, const float* __restrict__ g,
    const float* __restrict__ bb, const float* __restrict__ w,
    const float* __restrict__ bias0, float* __restrict__ out) {
    __shared__ float red[8];
    int token = blockIdx.x, tid = threadIdx.x;
    float v0 = h[token * 512 + tid], v1 = h[token * 512 + tid + 256];
    float s  = block_reduce_sum_256(v0 + v1, red);
    float ss = block_reduce_sum_256(v0 * v0 + v1 * v1, red);
    float mu = s * (1.f / 512.f);
    float var = ss * (1.f / 512.f) - mu * mu;
    float inv = rsqrtf(var + EPS);
    float n0 = (v0 - mu) * inv * g[tid] + bb[tid];
    float n1 = (v1 - mu) * inv * g[tid + 256] + bb[tid + 256];
    float dot = block_reduce_sum_256(n0 * w[tid] + n1 * w[tid + 256], red);
    if (tid == 0) out[token] = dot + bias0[0];
}

// ---------------------------------------------------------------------------
extern "C" void kernel_launch(void* const* d_in, const int* in_sizes, int n_in,
                              void* d_out, int out_size, void* d_ws, size_t ws_size,
                              hipStream_t stream) {
    const float* x       = (const float*)d_in[0];
    const float* z       = (const float*)d_in[1];
    const float* conv_w  = (const float*)d_in[2];
    const float* conv_b  = (const float*)d_in[3];
    const float* tok_g   = (const float*)d_in[4];
    const float* tok_b   = (const float*)d_in[5];
    const float* film_w  = (const float*)d_in[6];
    const float* film_b  = (const float*)d_in[7];
    const float* ln1_g   = (const float*)d_in[8];
    const float* ln1_b   = (const float*)d_in[9];
    const float* kqv_w   = (const float*)d_in[10];
    const float* kqv_b   = (const float*)d_in[11];
    const float* proj_w  = (const float*)d_in[12];
    const float* proj_b  = (const float*)d_in[13];
    const float* ln2_g   = (const float*)d_in[14];
    const float* ln2_b   = (const float*)d_in[15];
    const float* mlp_w1  = (const float*)d_in[16];
    const float* mlp_b1  = (const float*)d_in[17];
    const float* mlp_w2  = (const float*)d_in[18];
    const float* mlp_b2  = (const float*)d_in[19];
    const float* rs_attn = (const float*)d_in[20];
    const float* rs_mlp  = (const float*)d_in[21];
    const float* head_g  = (const float*)d_in[22];
    const float* head_b  = (const float*)d_in[23];
    const float* head_w  = (const float*)d_in[24];
    const float* head_bs = (const float*)d_in[25];
    float* out = (float*)d_out;

    float* ws = (float*)d_ws;
    float* gb   = ws;                  // 524288 f
    float* h    = gb + 524288;         // 262144 f
    float* kqvf = h + 262144;          // 786432 f
    short* sb = (short*)(kqvf + 786432);
    short* wbf   = sb;                 // 294912
    short* kqvT  = wbf   + 294912;     // 4718592
    short* projT = kqvT  + 4718592;    // 1572864
    short* mlp1T = projT + 1572864;    // 6291456
    short* mlp2T = mlp1T + 6291456;    // 6291456
    short* tokb  = mlp2T + 6291456;    // 16777216
    short* yvb   = tokb  + 16777216;   // 262144
    short* mbuf  = yvb   + 262144;     // 1048576
    short* xbf   = mbuf  + 1048576;    // 6291456

    film_kernel<<<512, 256, 0, stream>>>(z, film_w, film_b, gb);
    cvt_kernel<<<1152, 256, 0, stream>>>(conv_w, wbf, 294912);
    xcast_kernel<<<3072, 256, 0, stream>>>(x, xbf, 786432);
    tcast_kernel<<<dim3(48, 16, 6), 256, 0, stream>>>(kqv_w, kqvT, 512, 1536);
    tcast_kernel<<<dim3(16, 16, 6), 256, 0, stream>>>(proj_w, projT, 512, 512);
    tcast_kernel<<<dim3(64, 16, 6), 256, 0, stream>>>(mlp_w1, mlp1T, 512, 2048);
    tcast_kernel<<<dim3(16, 64, 6), 256, 0, stream>>>(mlp_w2, mlp2T, 2048, 512);

    conv_gemm<<<dim3(4, 256), 256, 0, stream>>>(xbf, wbf, conv_b, tokb);
    tok_post<<<512, 256, 0, stream>>>(tokb, tok_g, tok_b, gb, h);

    for (int i = 0; i < 6; i++) {
        gemm_ln<<<dim3(12, 16), 256, 0, stream>>>(
            h, ln1_g + i * 512, ln1_b + i * 512,
            kqvT + (size_t)i * 1536 * 512, kqv_b + i * 1536,
            1536, 0, kqvf, nullptr);
        attn_kernel<<<128, 256, 0, stream>>>(kqvf, yvb);
        gemm_res<<<dim3(8, 16), 256, 0, stream>>>(
            yvb, projT + (size_t)i * 512 * 512, proj_b + i * 512,
            rs_attn + i, h, 512);
        gemm_ln<<<dim3(16, 16), 256, 0, stream>>>(
            h, ln2_g + i * 512, ln2_b + i * 512,
            mlp1T + (size_t)i * 2048 * 512, mlp_b1 + i * 2048,
            2048, 1, nullptr, mbuf);
        gemm_res<<<dim3(8, 16), 256, 0, stream>>>(
            mbuf, mlp2T + (size_t)i * 512 * 2048, mlp_b2 + i * 512,
            rs_mlp + i, h, 2048);
    }

    head_kernel<<<512, 256, 0, stream>>>(h, head_g, head_b, head_w, head_bs, out);
}

// Round 6
// 549.840 us; speedup vs baseline: 2.5935x; 1.0560x over previous
//
#include <hip/hip_runtime.h>
#include <math.h>

#define EPS 1e-5f

typedef __attribute__((ext_vector_type(8))) short short8;
typedef __attribute__((ext_vector_type(4))) float f32x4;

__device__ __forceinline__ short f2bf(float f) {
    unsigned u = __float_as_uint(f);
    u += 0x7fffu + ((u >> 16) & 1u);
    return (short)(u >> 16);
}
__device__ __forceinline__ float bf2f(short s) {
    return __uint_as_float(((unsigned)(unsigned short)s) << 16);
}
__device__ __forceinline__ void async16(const void* g, void* l) {
    __builtin_amdgcn_global_load_lds(
        (const __attribute__((address_space(1))) unsigned*)g,
        (__attribute__((address_space(3))) unsigned*)l, 16, 0, 0);
}

// ---------------------------------------------------------------------------
__device__ __forceinline__ float block_reduce_sum_256(float v, float* red) {
    #pragma unroll
    for (int o = 32; o > 0; o >>= 1) v += __shfl_down(v, o, 64);
    __syncthreads();
    if ((threadIdx.x & 63) == 0) red[threadIdx.x >> 6] = v;
    __syncthreads();
    return red[0] + red[1] + red[2] + red[3];
}

// ---------------------------------------------------------------------------
// prep_misc: [0,512) film GEMM; [512,1664) conv_w cast; [1664,4736) x cast.
__global__ __launch_bounds__(256) void prep_misc(
    const float* __restrict__ z, const float* __restrict__ fw,
    const float* __restrict__ fb, float* __restrict__ gb,
    const float* __restrict__ conv_w, short* __restrict__ wbf,
    const float* __restrict__ x, short* __restrict__ xbf) {
    __shared__ float zs[32];
    int bi = blockIdx.x, tid = threadIdx.x;
    if (bi < 512) {
        if (tid < 32) zs[tid] = z[bi * 32 + tid];
        __syncthreads();
        for (int j = tid; j < 1024; j += 256) {
            float acc = fb[j];
            #pragma unroll
            for (int k = 0; k < 32; k++) acc = fmaf(zs[k], fw[k * 1024 + j], acc);
            gb[bi * 1024 + j] = acc;
        }
    } else if (bi < 1664) {
        int i = (bi - 512) * 256 + tid;          // 294912 total
        wbf[i] = f2bf(conv_w[i]);
    } else {
        int i = (bi - 1664) * 256 + tid;         // 786432 chunks of 8
        float4 a = *(const float4*)(x + (size_t)i * 8);
        float4 b = *(const float4*)(x + (size_t)i * 8 + 4);
        short8 o = {f2bf(a.x), f2bf(a.y), f2bf(a.z), f2bf(a.w),
                    f2bf(b.x), f2bf(b.y), f2bf(b.z), f2bf(b.w)};
        *(short8*)(xbf + (size_t)i * 8) = o;
    }
}

// ---------------------------------------------------------------------------
// prep_tcast: all 4 weight families, fp32 [L][K][N] -> bf16 [L][N][K].
// tiles: kqv 4608 | proj 1536 | mlp1 6144 | mlp2 6144  (total 18432)
__global__ __launch_bounds__(256) void prep_tcast(
    const float* __restrict__ kqv_w, short* __restrict__ kqvT,
    const float* __restrict__ proj_w, short* __restrict__ projT,
    const float* __restrict__ mlp_w1, short* __restrict__ mlp1T,
    const float* __restrict__ mlp_w2, short* __restrict__ mlp2T) {
    __shared__ float tile[32][33];
    int bi = blockIdx.x;
    const float* src; short* dst; int NT, K, N, rel;
    if (bi < 4608)       { src = kqv_w;  dst = kqvT;  NT = 48; K = 512;  N = 1536; rel = bi; }
    else if (bi < 6144)  { src = proj_w; dst = projT; NT = 16; K = 512;  N = 512;  rel = bi - 4608; }
    else if (bi < 12288) { src = mlp_w1; dst = mlp1T; NT = 64; K = 512;  N = 2048; rel = bi - 6144; }
    else                 { src = mlp_w2; dst = mlp2T; NT = 16; K = 2048; N = 512;  rel = bi - 12288; }
    int per = NT * (K / 32);
    int layer = rel / per, r2 = rel - layer * per;
    int nt = r2 % NT, kt = r2 / NT;
    src += (size_t)layer * K * N;
    dst += (size_t)layer * N * K;
    int n0 = nt * 32, k0 = kt * 32;
    int lx = threadIdx.x & 31, ly = threadIdx.x >> 5;
    #pragma unroll
    for (int i = 0; i < 32; i += 8)
        tile[ly + i][lx] = src[(size_t)(k0 + ly + i) * N + n0 + lx];
    __syncthreads();
    #pragma unroll
    for (int i = 0; i < 32; i += 8)
        dst[(size_t)(n0 + ly + i) * K + k0 + lx] = f2bf(tile[lx][ly + i]);
}

// ---------------------------------------------------------------------------
// Conv as GEMM, 128x128 tile, BK=64, XOR-swizzled LDS chunks (W=8).
__global__ __launch_bounds__(256) void conv_gemm(
    const short* __restrict__ xbf, const short* __restrict__ wbf,
    const float* __restrict__ cb, short* __restrict__ tok) {
    __shared__ short As[128 * 64];
    __shared__ short Bs[128 * 64];
    int tid = threadIdx.x;
    int n0 = blockIdx.x * 128, m0 = blockIdx.y * 128;
    int wave = tid >> 6, lane = tid & 63, quad = lane >> 4, l16 = lane & 15;
    int wm = wave & 1, wn = wave >> 1;

    int segA[4], tA[4];
    long long base0[4];
    #pragma unroll
    for (int e = 0; e < 4; e++) {
        int p = e * 256 + tid;
        int row = p >> 3;
        segA[e] = (p & 7) ^ (row & 7);
        int m = m0 + row;
        int bt = m >> 6, nn = m & 63;
        int b = bt >> 5, t = bt & 31;
        int hn = nn >> 3, wn2 = nn & 7;
        tA[e] = t;
        base0[e] = (((long long)(b * 32 + t - 2) * 3) << 12)
                   + (long long)(hn * 8) * 64 + wn2 * 8;
    }

    f32x4 acc[4][4];
    #pragma unroll
    for (int mt = 0; mt < 4; mt++)
        #pragma unroll
        for (int nt = 0; nt < 4; nt++) acc[mt][nt] = (f32x4){0.f, 0.f, 0.f, 0.f};

    for (int k0 = 0; k0 < 576; k0 += 64) {
        #pragma unroll
        for (int e = 0; e < 4; e++) {
            int p = e * 256 + tid;
            int n = p >> 3, seg = (p & 7) ^ (n & 7);
            async16(wbf + (size_t)(n0 + n) * 576 + k0 + seg * 8, Bs + p * 8);
        }
        #pragma unroll
        for (int e = 0; e < 4; e++) {
            int p = e * 256 + tid;
            int ks = (k0 >> 3) + segA[e];
            int ch = (ks >= 24) + (ks >= 48);
            int r = ks - ch * 24;
            int kt = r >> 3, ph = r & 7;
            short8 v8 = (short8){0, 0, 0, 0, 0, 0, 0, 0};
            if (tA[e] + kt >= 2)
                v8 = *(const short8*)(xbf + base0[e]
                        + ((long long)(kt * 3 + ch) << 12) + ph * 64);
            *(short8*)(As + p * 8) = v8;
        }
        __syncthreads();
        #pragma unroll
        for (int ksub = 0; ksub < 2; ksub++) {
            int ccb = ksub * 4 + quad;
            short8 af[4], bf[4];
            #pragma unroll
            for (int mt = 0; mt < 4; mt++) {
                int row = wm * 64 + mt * 16 + l16;
                af[mt] = *(const short8*)(As + (row * 8 + (ccb ^ (row & 7))) * 8);
            }
            #pragma unroll
            for (int nt = 0; nt < 4; nt++) {
                int row = wn * 64 + nt * 16 + l16;
                bf[nt] = *(const short8*)(Bs + (row * 8 + (ccb ^ (row & 7))) * 8);
            }
            #pragma unroll
            for (int mt = 0; mt < 4; mt++)
                #pragma unroll
                for (int nt = 0; nt < 4; nt++)
                    acc[mt][nt] = __builtin_amdgcn_mfma_f32_16x16x32_bf16(
                        af[mt], bf[nt], acc[mt][nt], 0, 0, 0);
        }
        __syncthreads();
    }
    #pragma unroll
    for (int mt = 0; mt < 4; mt++)
        #pragma unroll
        for (int nt = 0; nt < 4; nt++)
            #pragma unroll
            for (int reg = 0; reg < 4; reg++) {
                int m = m0 + wm * 64 + mt * 16 + quad * 4 + reg;
                int n = n0 + wn * 64 + nt * 16 + l16;
                tok[(size_t)m * 512 + n] = f2bf(acc[mt][nt][reg] + cb[n]);
            }
}

// ---------------------------------------------------------------------------
// tok_post: per (b,t): LN over 512 ch for each of 64 tokens + FiLM + mean -> h
__global__ __launch_bounds__(256) void tok_post(
    const short* __restrict__ tok, const float* __restrict__ tg,
    const float* __restrict__ tb, const float* __restrict__ gb,
    float* __restrict__ h) {
    __shared__ float mu_s[64], inv_s[64];
    __shared__ float red[4][512];
    int bt = blockIdx.x, tid = threadIdx.x;
    int wave = tid >> 6, lane = tid & 63;
    {
        int tokn = wave * 16 + (lane >> 2), part = lane & 3;
        const short* p = tok + (size_t)(bt * 64 + tokn) * 512 + part * 128;
        float s = 0.f, ss = 0.f;
        #pragma unroll
        for (int i = 0; i < 16; i++) {
            short8 v = *(const short8*)(p + i * 8);
            #pragma unroll
            for (int j = 0; j < 8; j++) {
                float f = bf2f(v[j]);
                s += f; ss += f * f;
            }
        }
        s += __shfl_xor(s, 1, 64); ss += __shfl_xor(ss, 1, 64);
        s += __shfl_xor(s, 2, 64); ss += __shfl_xor(ss, 2, 64);
        if (part == 0) {
            float mu = s * (1.f / 512.f);
            float var = ss * (1.f / 512.f) - mu * mu;
            mu_s[tokn] = mu;
            inv_s[tokn] = rsqrtf(var + EPS);
        }
    }
    __syncthreads();
    float hacc[8] = {0.f, 0.f, 0.f, 0.f, 0.f, 0.f, 0.f, 0.f};
    int c0 = lane * 8;
    for (int it = 0; it < 16; it++) {
        int n = it * 4 + wave;
        float mu = mu_s[n], inv = inv_s[n];
        short8 v = *(const short8*)(tok + (size_t)(bt * 64 + n) * 512 + c0);
        #pragma unroll
        for (int j = 0; j < 8; j++) hacc[j] += (bf2f(v[j]) - mu) * inv;
    }
    #pragma unroll
    for (int j = 0; j < 8; j++) red[wave][c0 + j] = hacc[j];
    __syncthreads();
    #pragma unroll
    for (int cc = 0; cc < 2; cc++) {
        int c = tid + cc * 256;
        float S = red[0][c] + red[1][c] + red[2][c] + red[3][c];
        float G  = 1.f + 0.5f * gb[bt * 1024 + c];
        float Be = 0.5f * gb[bt * 1024 + 512 + c];
        h[bt * 512 + c] = G * (tg[c] * (S * (1.f / 64.f)) + tb[c]) + Be;
    }
}

// ---------------------------------------------------------------------------
// attn_fused: one block per (b, head). LN(h rows of b) -> kqv GEMM for this
// head's 192 columns -> RoPE -> causal softmax -> PV -> yv bf16.
// LDS: As 32KB (full-K LN'd A) | Bs 24KB (192 x BK=64). Attn arrays overlay.
__global__ __launch_bounds__(256) void attn_fused(
    const float* __restrict__ hsrc, const float* __restrict__ lng,
    const float* __restrict__ lnb, const short* __restrict__ Bw,
    const float* __restrict__ bias, short* __restrict__ yv) {
    __shared__ char smem[57344] __attribute__((aligned(16)));
    __shared__ float mu_s[32], inv_s[32];
    short* As = (short*)smem;                      // 32*512*2 = 32768
    short* Bs = (short*)(smem + 32768);            // 192*64*2 = 24576
    float (*qs)[64] = (float(*)[64])(smem);
    float (*ks)[64] = (float(*)[64])(smem + 8192);
    float (*vs)[64] = (float(*)[64])(smem + 16384);
    float (*qr)[64] = (float(*)[64])(smem + 24576);
    float (*kr)[64] = (float(*)[64])(smem + 32768);
    float (*att)[32] = (float(*)[32])(smem + 40960);
    int blk = blockIdx.x, b = blk >> 3, hh = blk & 7;
    int tid = threadIdx.x;
    int m0 = b * 32;
    // LN pass 1
    {
        int row = tid >> 3, l8 = tid & 7;
        const float* hp = hsrc + (size_t)(m0 + row) * 512 + l8 * 64;
        float s = 0.f, ss = 0.f;
        #pragma unroll
        for (int i = 0; i < 16; i++) {
            float4 v = *(const float4*)(hp + i * 4);
            s += v.x + v.y + v.z + v.w;
            ss += v.x * v.x + v.y * v.y + v.z * v.z + v.w * v.w;
        }
        s += __shfl_xor(s, 1, 64); ss += __shfl_xor(ss, 1, 64);
        s += __shfl_xor(s, 2, 64); ss += __shfl_xor(ss, 2, 64);
        s += __shfl_xor(s, 4, 64); ss += __shfl_xor(ss, 4, 64);
        if (l8 == 0) {
            float mu = s * (1.f / 512.f);
            float var = ss * (1.f / 512.f) - mu * mu;
            mu_s[row] = mu;
            inv_s[row] = rsqrtf(var + EPS);
        }
    }
    __syncthreads();
    // LN pass 2 -> As (full K, swizzle W=8 over 64 chunks)
    #pragma unroll
    for (int e = 0; e < 8; e++) {
        int lc = e * 256 + tid;
        int row = lc >> 6, cc = lc & 63;
        float mu = mu_s[row], inv = inv_s[row];
        const float* hp = hsrc + (size_t)(m0 + row) * 512 + cc * 8;
        float4 a = *(const float4*)hp, b2 = *(const float4*)(hp + 4);
        float4 g0 = *(const float4*)(lng + cc * 8), g1 = *(const float4*)(lng + cc * 8 + 4);
        float4 b0 = *(const float4*)(lnb + cc * 8), b1 = *(const float4*)(lnb + cc * 8 + 4);
        short8 o = {f2bf((a.x - mu) * inv * g0.x + b0.x),
                    f2bf((a.y - mu) * inv * g0.y + b0.y),
                    f2bf((a.z - mu) * inv * g0.z + b0.z),
                    f2bf((a.w - mu) * inv * g0.w + b0.w),
                    f2bf((b2.x - mu) * inv * g1.x + b1.x),
                    f2bf((b2.y - mu) * inv * g1.y + b1.y),
                    f2bf((b2.z - mu) * inv * g1.z + b1.z),
                    f2bf((b2.w - mu) * inv * g1.w + b1.w)};
        *(short8*)(As + (row * 64 + (cc ^ (row & 7))) * 8) = o;
    }
    __syncthreads();
    // GEMM: 32m x 192n (wave w covers d-cols [w*16,w*16+16) for k,q,v)
    int wave = tid >> 6, lane = tid & 63, quad = lane >> 4, l16 = lane & 15;
    f32x4 acc[2][3];
    #pragma unroll
    for (int m2 = 0; m2 < 2; m2++)
        #pragma unroll
        for (int g = 0; g < 3; g++) acc[m2][g] = (f32x4){0.f, 0.f, 0.f, 0.f};
    for (int k0 = 0; k0 < 512; k0 += 64) {
        #pragma unroll
        for (int e = 0; e < 6; e++) {       // 192 rows x 8 chunks = 1536
            int p = e * 256 + tid;
            int row = p >> 3, seg = (p & 7) ^ (row & 7);
            int n = ((row >> 6) << 9) + hh * 64 + (row & 63);
            async16(Bw + (size_t)n * 512 + k0 + seg * 8, Bs + p * 8);
        }
        __syncthreads();
        #pragma unroll
        for (int ksub = 0; ksub < 2; ksub++) {
            int ccb = ksub * 4 + quad;
            short8 af[2], bf[3];
            #pragma unroll
            for (int m2 = 0; m2 < 2; m2++) {
                int row = m2 * 16 + l16;
                int cc = (k0 >> 3) + ccb;
                af[m2] = *(const short8*)(As + (row * 64 + (cc ^ (row & 7))) * 8);
            }
            #pragma unroll
            for (int g = 0; g < 3; g++) {
                int row = g * 64 + wave * 16 + l16;
                bf[g] = *(const short8*)(Bs + (row * 8 + (ccb ^ (row & 7))) * 8);
            }
            #pragma unroll
            for (int m2 = 0; m2 < 2; m2++)
                #pragma unroll
                for (int g = 0; g < 3; g++)
                    acc[m2][g] = __builtin_amdgcn_mfma_f32_16x16x32_bf16(
                        af[m2], bf[g], acc[m2][g], 0, 0, 0);
        }
        __syncthreads();
    }
    // epilogue -> k/q/v fp32 in LDS (overlays As/Bs; all reads done)
    float bb0 = bias[hh * 64 + wave * 16 + l16];
    float bb1 = bias[512 + hh * 64 + wave * 16 + l16];
    float bb2 = bias[1024 + hh * 64 + wave * 16 + l16];
    int dcol = wave * 16 + l16;
    #pragma unroll
    for (int m2 = 0; m2 < 2; m2++)
        #pragma unroll
        for (int reg = 0; reg < 4; reg++) {
            int tkn = m2 * 16 + quad * 4 + reg;
            ks[tkn][dcol] = acc[m2][0][reg] + bb0;
            qs[tkn][dcol] = acc[m2][1][reg] + bb1;
            vs[tkn][dcol] = acc[m2][2][reg] + bb2;
        }
    __syncthreads();
    // RoPE
    const float lnb_c = logf(10000.f) / 32.f;
    for (int idx = tid; idx < 2048; idx += 256) {
        int t = idx >> 6, d = idx & 63;
        int j = d & 31;
        float ang = (float)t * expf(-(float)j * lnb_c);
        float sv = sinf(ang), cv = cosf(ang);
        float qv = qs[t][d], kv = ks[t][d];
        float qo = qs[t][d ^ 32], ko = ks[t][d ^ 32];
        float rq = (d < 32) ? -qo : qo;
        float rk = (d < 32) ? -ko : ko;
        qr[t][d] = qv * cv + rq * sv;
        kr[t][d] = kv * cv + rk * sv;
    }
    __syncthreads();
    // scores + causal
    #pragma unroll
    for (int l = 0; l < 4; l++) {
        int idx = l * 256 + tid;
        int qt = idx >> 5, kt2 = idx & 31;
        float s;
        if (kt2 > qt) {
            s = -1e30f;
        } else {
            float a = 0.f;
            #pragma unroll
            for (int d = 0; d < 64; d++) a = fmaf(qr[qt][d], kr[kt2][d], a);
            s = a * 0.125f;
        }
        att[qt][kt2] = s;
    }
    __syncthreads();
    if (tid < 32) {
        float m = -1e30f;
        #pragma unroll
        for (int k = 0; k < 32; k++) m = fmaxf(m, att[tid][k]);
        float sum = 0.f;
        #pragma unroll
        for (int k = 0; k < 32; k++) {
            float e = expf(att[tid][k] - m);
            att[tid][k] = e;
            sum += e;
        }
        float inv = 1.f / sum;
        #pragma unroll
        for (int k = 0; k < 32; k++) att[tid][k] *= inv;
    }
    __syncthreads();
    for (int idx = tid; idx < 2048; idx += 256) {
        int t = idx >> 6, d = idx & 63;
        float a = 0.f;
        #pragma unroll
        for (int k = 0; k < 32; k++) a = fmaf(att[t][k], vs[k][d], a);
        yv[(size_t)(b * 32 + t) * 512 + hh * 64 + d] = f2bf(a);
    }
}

// ---------------------------------------------------------------------------
// gemm_ln: LN(h 32-row tile) -> As (full K=512, swizzle W=64), B streamed
// bf16 [N][512], BK=128 (swizzle W=16). Tile 32m x 128n.
// mode 0: outf = acc + bias (fp32). mode 1: GELU -> outb (bf16).
__global__ __launch_bounds__(256) void gemm_ln(
    const float* __restrict__ hsrc, const float* __restrict__ lng,
    const float* __restrict__ lnb, const short* __restrict__ Bw,
    const float* __restrict__ bias, int N, int mode,
    float* __restrict__ outf, short* __restrict__ outb) {
    __shared__ short As[32 * 512];
    __shared__ short Bs[128 * 128];
    __shared__ float mu_s[32], inv_s[32];
    int tid = threadIdx.x;
    int m0 = blockIdx.y * 32, n0 = blockIdx.x * 128;
    {
        int row = tid >> 3, l8 = tid & 7;
        const float* hp = hsrc + (size_t)(m0 + row) * 512 + l8 * 64;
        float s = 0.f, ss = 0.f;
        #pragma unroll
        for (int i = 0; i < 16; i++) {
            float4 v = *(const float4*)(hp + i * 4);
            s += v.x + v.y + v.z + v.w;
            ss += v.x * v.x + v.y * v.y + v.z * v.z + v.w * v.w;
        }
        s += __shfl_xor(s, 1, 64); ss += __shfl_xor(ss, 1, 64);
        s += __shfl_xor(s, 2, 64); ss += __shfl_xor(ss, 2, 64);
        s += __shfl_xor(s, 4, 64); ss += __shfl_xor(ss, 4, 64);
        if (l8 == 0) {
            float mu = s * (1.f / 512.f);
            float var = ss * (1.f / 512.f) - mu * mu;
            mu_s[row] = mu;
            inv_s[row] = rsqrtf(var + EPS);
        }
    }
    __syncthreads();
    #pragma unroll
    for (int e = 0; e < 8; e++) {
        int lc = e * 256 + tid;
        int row = lc >> 6, cc = lc & 63;
        float mu = mu_s[row], inv = inv_s[row];
        const float* hp = hsrc + (size_t)(m0 + row) * 512 + cc * 8;
        float4 a = *(const float4*)hp, b = *(const float4*)(hp + 4);
        float4 g0 = *(const float4*)(lng + cc * 8), g1 = *(const float4*)(lng + cc * 8 + 4);
        float4 b0 = *(const float4*)(lnb + cc * 8), b1 = *(const float4*)(lnb + cc * 8 + 4);
        short8 o = {f2bf((a.x - mu) * inv * g0.x + b0.x),
                    f2bf((a.y - mu) * inv * g0.y + b0.y),
                    f2bf((a.z - mu) * inv * g0.z + b0.z),
                    f2bf((a.w - mu) * inv * g0.w + b0.w),
                    f2bf((b.x - mu) * inv * g1.x + b1.x),
                    f2bf((b.y - mu) * inv * g1.y + b1.y),
                    f2bf((b.z - mu) * inv * g1.z + b1.z),
                    f2bf((b.w - mu) * inv * g1.w + b1.w)};
        *(short8*)(As + (row * 64 + (cc ^ (row & 7))) * 8) = o;
    }
    __syncthreads();
    int wave = tid >> 6, lane = tid & 63, quad = lane >> 4, l16 = lane & 15;
    f32x4 acc[2][2];
    #pragma unroll
    for (int a2 = 0; a2 < 2; a2++)
        #pragma unroll
        for (int b2 = 0; b2 < 2; b2++) acc[a2][b2] = (f32x4){0.f, 0.f, 0.f, 0.f};
    for (int k0 = 0; k0 < 512; k0 += 128) {
        #pragma unroll
        for (int e = 0; e < 8; e++) {
            int p = e * 256 + tid;
            int row = p >> 4, seg = (p & 15) ^ (row & 15);
            async16(Bw + (size_t)(n0 + row) * 512 + k0 + seg * 8, Bs + p * 8);
        }
        __syncthreads();
        #pragma unroll
        for (int ksub = 0; ksub < 4; ksub++) {
            int ccb = ksub * 4 + quad;
            short8 af[2], bf[2];
            #pragma unroll
            for (int m2 = 0; m2 < 2; m2++) {
                int row = m2 * 16 + l16;
                int cc = (k0 >> 3) + ccb;
                af[m2] = *(const short8*)(As + (row * 64 + (cc ^ (row & 7))) * 8);
            }
            #pragma unroll
            for (int n2 = 0; n2 < 2; n2++) {
                int row = wave * 32 + n2 * 16 + l16;
                bf[n2] = *(const short8*)(Bs + (row * 16 + (ccb ^ (row & 15))) * 8);
            }
            #pragma unroll
            for (int m2 = 0; m2 < 2; m2++)
                #pragma unroll
                for (int n2 = 0; n2 < 2; n2++)
                    acc[m2][n2] = __builtin_amdgcn_mfma_f32_16x16x32_bf16(
                        af[m2], bf[n2], acc[m2][n2], 0, 0, 0);
        }
        __syncthreads();
    }
    #pragma unroll
    for (int m2 = 0; m2 < 2; m2++)
        #pragma unroll
        for (int n2 = 0; n2 < 2; n2++)
            #pragma unroll
            for (int reg = 0; reg < 4; reg++) {
                int m = m0 + m2 * 16 + quad * 4 + reg;
                int n = n0 + wave * 32 + n2 * 16 + l16;
                float v = acc[m2][n2][reg] + bias[n];
                if (mode == 1) {
                    v = 0.5f * v * (1.f + erff(v * 0.70710678118f));
                    outb[(size_t)m * N + n] = f2bf(v);
                } else {
                    outf[(size_t)m * N + n] = v;
                }
            }
}

// ---------------------------------------------------------------------------
// gemm_res: A[M][K] bf16, B[N][K] bf16, BK=128 (swizzle W=16).
// Tile 32m x 64n, output N=512: h[m][n] += rs * (acc + bias).
__global__ __launch_bounds__(256) void gemm_res(
    const short* __restrict__ Ag, const short* __restrict__ Bw,
    const float* __restrict__ bias, const float* __restrict__ rsPtr,
    float* __restrict__ hm, int K) {
    __shared__ short As[32 * 128];
    __shared__ short Bs[64 * 128];
    int tid = threadIdx.x;
    int m0 = blockIdx.y * 32, n0 = blockIdx.x * 64;
    int wave = tid >> 6, lane = tid & 63, quad = lane >> 4, l16 = lane & 15;
    f32x4 acc[2];
    acc[0] = (f32x4){0.f, 0.f, 0.f, 0.f};
    acc[1] = (f32x4){0.f, 0.f, 0.f, 0.f};
    for (int k0 = 0; k0 < K; k0 += 128) {
        #pragma unroll
        for (int e = 0; e < 2; e++) {
            int p = e * 256 + tid;
            int row = p >> 4, seg = (p & 15) ^ (row & 15);
            async16(Ag + (size_t)(m0 + row) * K + k0 + seg * 8, As + p * 8);
        }
        #pragma unroll
        for (int e = 0; e < 4; e++) {
            int p = e * 256 + tid;
            int row = p >> 4, seg = (p & 15) ^ (row & 15);
            async16(Bw + (size_t)(n0 + row) * K + k0 + seg * 8, Bs + p * 8);
        }
        __syncthreads();
        #pragma unroll
        for (int ksub = 0; ksub < 4; ksub++) {
            int ccb = ksub * 4 + quad;
            short8 bf;
            {
                int row = wave * 16 + l16;
                bf = *(const short8*)(Bs + (row * 16 + (ccb ^ (row & 15))) * 8);
            }
            #pragma unroll
            for (int m2 = 0; m2 < 2; m2++) {
                int row = m2 * 16 + l16;
                short8 af = *(const short8*)(As + (row * 16 + (ccb ^ (row & 15))) * 8);
                acc[m2] = __builtin_amdgcn_mfma_f32_16x16x32_bf16(af, bf, acc[m2], 0, 0, 0);
            }
        }
        __syncthreads();
    }
    float rsv = *rsPtr;
    #pragma unroll
    for (int m2 = 0; m2 < 2; m2++)
        #pragma unroll
        for (int reg = 0; reg < 4; reg++) {
            int m = m0 + m2 * 16 + quad * 4 + reg;
            int n = n0 + wave * 16 + l16;
            size_t off = (size_t)m * 512 + n;
            hm[off] = hm[off] + rsv * (acc[m2][reg] + bias[n]);
        }
}

// ---------------------------------------------------------------------------
__global__ __launch_bounds__(256) void head_kernel(
    const float* __restrict__ h, const float* __restrict__ g,
    const float* __restrict__ bb, const float* __restrict__ w,
    const float* __restrict__ bias0, float* __restrict__ out) {
    __shared__ float red[8];
    int token = blockIdx.x, tid = threadIdx.x;
    float v0 = h[token * 512 + tid], v1 = h[token * 512 + tid + 256];
    float s  = block_reduce_sum_256(v0 + v1, red);
    float ss = block_reduce_sum_256(v0 * v0 + v1 * v1, red);
    float mu = s * (1.f / 512.f);
    float var = ss * (1.f / 512.f) - mu * mu;
    float inv = rsqrtf(var + EPS);
    float n0 = (v0 - mu) * inv * g[tid] + bb[tid];
    float n1 = (v1 - mu) * inv * g[tid + 256] + bb[tid + 256];
    float dot = block_reduce_sum_256(n0 * w[tid] + n1 * w[tid + 256], red);
    if (tid == 0) out[token] = dot + bias0[0];
}

// ---------------------------------------------------------------------------
extern "C" void kernel_launch(void* const* d_in, const int* in_sizes, int n_in,
                              void* d_out, int out_size, void* d_ws, size_t ws_size,
                              hipStream_t stream) {
    const float* x       = (const float*)d_in[0];
    const float* z       = (const float*)d_in[1];
    const float* conv_w  = (const float*)d_in[2];
    const float* conv_b  = (const float*)d_in[3];
    const float* tok_g   = (const float*)d_in[4];
    const float* tok_b   = (const float*)d_in[5];
    const float* film_w  = (const float*)d_in[6];
    const float* film_b  = (const float*)d_in[7];
    const float* ln1_g   = (const float*)d_in[8];
    const float* ln1_b   = (const float*)d_in[9];
    const float* kqv_w   = (const float*)d_in[10];
    const float* kqv_b   = (const float*)d_in[11];
    const float* proj_w  = (const float*)d_in[12];
    const float* proj_b  = (const float*)d_in[13];
    const float* ln2_g   = (const float*)d_in[14];
    const float* ln2_b   = (const float*)d_in[15];
    const float* mlp_w1  = (const float*)d_in[16];
    const float* mlp_b1  = (const float*)d_in[17];
    const float* mlp_w2  = (const float*)d_in[18];
    const float* mlp_b2  = (const float*)d_in[19];
    const float* rs_attn = (const float*)d_in[20];
    const float* rs_mlp  = (const float*)d_in[21];
    const float* head_g  = (const float*)d_in[22];
    const float* head_b  = (const float*)d_in[23];
    const float* head_w  = (const float*)d_in[24];
    const float* head_bs = (const float*)d_in[25];
    float* out = (float*)d_out;

    float* ws = (float*)d_ws;
    float* gb   = ws;                  // 524288 f
    float* h    = gb + 524288;         // 262144 f
    short* sb = (short*)(h + 262144);
    short* wbf   = sb;                 // 294912
    short* kqvT  = wbf   + 294912;     // 4718592
    short* projT = kqvT  + 4718592;    // 1572864
    short* mlp1T = projT + 1572864;    // 6291456
    short* mlp2T = mlp1T + 6291456;    // 6291456
    short* tokb  = mlp2T + 6291456;    // 16777216
    short* yvb   = tokb  + 16777216;   // 262144
    short* mbuf  = yvb   + 262144;     // 1048576
    short* xbf   = mbuf  + 1048576;    // 6291456

    prep_misc<<<4736, 256, 0, stream>>>(z, film_w, film_b, gb, conv_w, wbf, x, xbf);
    prep_tcast<<<18432, 256, 0, stream>>>(kqv_w, kqvT, proj_w, projT,
                                          mlp_w1, mlp1T, mlp_w2, mlp2T);

    conv_gemm<<<dim3(4, 256), 256, 0, stream>>>(xbf, wbf, conv_b, tokb);
    tok_post<<<512, 256, 0, stream>>>(tokb, tok_g, tok_b, gb, h);

    for (int i = 0; i < 6; i++) {
        attn_fused<<<128, 256, 0, stream>>>(
            h, ln1_g + i * 512, ln1_b + i * 512,
            kqvT + (size_t)i * 1536 * 512, kqv_b + i * 1536, yvb);
        gemm_res<<<dim3(8, 16), 256, 0, stream>>>(
            yvb, projT + (size_t)i * 512 * 512, proj_b + i * 512,
            rs_attn + i, h, 512);
        gemm_ln<<<dim3(16, 16), 256, 0, stream>>>(
            h, ln2_g + i * 512, ln2_b + i * 512,
            mlp1T + (size_t)i * 2048 * 512, mlp_b1 + i * 2048,
            2048, 1, nullptr, mbuf);
        gemm_res<<<dim3(8, 16), 256, 0, stream>>>(
            mbuf, mlp2T + (size_t)i * 512 * 2048, mlp_b2 + i * 512,
            rs_mlp + i, h, 2048);
    }

    head_kernel<<<512, 256, 0, stream>>>(h, head_g, head_b, head_w, head_bs, out);
}

// Round 7
// 511.114 us; speedup vs baseline: 2.7900x; 1.0758x over previous
//
#include <hip/hip_runtime.h>
#include <math.h>

#define EPS 1e-5f

typedef __attribute__((ext_vector_type(8))) short short8;
typedef __attribute__((ext_vector_type(4))) float f32x4;

__device__ __forceinline__ short f2bf(float f) {
    unsigned u = __float_as_uint(f);
    u += 0x7fffu + ((u >> 16) & 1u);
    return (short)(u >> 16);
}
__device__ __forceinline__ float bf2f(short s) {
    return __uint_as_float(((unsigned)(unsigned short)s) << 16);
}
__device__ __forceinline__ void async16(const void* g, void* l) {
    __builtin_amdgcn_global_load_lds(
        (const __attribute__((address_space(1))) unsigned*)g,
        (__attribute__((address_space(3))) unsigned*)l, 16, 0, 0);
}

// ---------------------------------------------------------------------------
__device__ __forceinline__ float block_reduce_sum_256(float v, float* red) {
    #pragma unroll
    for (int o = 32; o > 0; o >>= 1) v += __shfl_down(v, o, 64);
    __syncthreads();
    if ((threadIdx.x & 63) == 0) red[threadIdx.x >> 6] = v;
    __syncthreads();
    return red[0] + red[1] + red[2] + red[3];
}

// ---------------------------------------------------------------------------
// prep_misc: [0,512) film GEMM; [512,1664) conv_w cast; [1664,4736) x cast.
__global__ __launch_bounds__(256) void prep_misc(
    const float* __restrict__ z, const float* __restrict__ fw,
    const float* __restrict__ fb, float* __restrict__ gb,
    const float* __restrict__ conv_w, short* __restrict__ wbf,
    const float* __restrict__ x, short* __restrict__ xbf) {
    __shared__ float zs[32];
    int bi = blockIdx.x, tid = threadIdx.x;
    if (bi < 512) {
        if (tid < 32) zs[tid] = z[bi * 32 + tid];
        __syncthreads();
        for (int j = tid; j < 1024; j += 256) {
            float acc = fb[j];
            #pragma unroll
            for (int k = 0; k < 32; k++) acc = fmaf(zs[k], fw[k * 1024 + j], acc);
            gb[bi * 1024 + j] = acc;
        }
    } else if (bi < 1664) {
        int i = (bi - 512) * 256 + tid;          // 294912 total
        wbf[i] = f2bf(conv_w[i]);
    } else {
        int i = (bi - 1664) * 256 + tid;         // 786432 chunks of 8
        float4 a = *(const float4*)(x + (size_t)i * 8);
        float4 b = *(const float4*)(x + (size_t)i * 8 + 4);
        short8 o = {f2bf(a.x), f2bf(a.y), f2bf(a.z), f2bf(a.w),
                    f2bf(b.x), f2bf(b.y), f2bf(b.z), f2bf(b.w)};
        *(short8*)(xbf + (size_t)i * 8) = o;
    }
}

// ---------------------------------------------------------------------------
// prep_tcast: all 4 weight families, fp32 [L][K][N] -> bf16 [L][N][K].
// tiles: kqv 4608 | proj 1536 | mlp1 6144 | mlp2 6144  (total 18432)
__global__ __launch_bounds__(256) void prep_tcast(
    const float* __restrict__ kqv_w, short* __restrict__ kqvT,
    const float* __restrict__ proj_w, short* __restrict__ projT,
    const float* __restrict__ mlp_w1, short* __restrict__ mlp1T,
    const float* __restrict__ mlp_w2, short* __restrict__ mlp2T) {
    __shared__ float tile[32][33];
    int bi = blockIdx.x;
    const float* src; short* dst; int NT, K, N, rel;
    if (bi < 4608)       { src = kqv_w;  dst = kqvT;  NT = 48; K = 512;  N = 1536; rel = bi; }
    else if (bi < 6144)  { src = proj_w; dst = projT; NT = 16; K = 512;  N = 512;  rel = bi - 4608; }
    else if (bi < 12288) { src = mlp_w1; dst = mlp1T; NT = 64; K = 512;  N = 2048; rel = bi - 6144; }
    else                 { src = mlp_w2; dst = mlp2T; NT = 16; K = 2048; N = 512;  rel = bi - 12288; }
    int per = NT * (K / 32);
    int layer = rel / per, r2 = rel - layer * per;
    int nt = r2 % NT, kt = r2 / NT;
    src += (size_t)layer * K * N;
    dst += (size_t)layer * N * K;
    int n0 = nt * 32, k0 = kt * 32;
    int lx = threadIdx.x & 31, ly = threadIdx.x >> 5;
    #pragma unroll
    for (int i = 0; i < 32; i += 8)
        tile[ly + i][lx] = src[(size_t)(k0 + ly + i) * N + n0 + lx];
    __syncthreads();
    // packed short2 writes: thread = (kp 0..15, n 0..15), 2 row passes
    int kp = threadIdx.x & 15, nn = threadIdx.x >> 4;
    #pragma unroll
    for (int i = 0; i < 2; i++) {
        int row = nn + i * 16;
        short2 o = {f2bf(tile[kp * 2][row]), f2bf(tile[kp * 2 + 1][row])};
        *(short2*)(dst + (size_t)(n0 + row) * K + k0 + kp * 2) = o;
    }
}

// ---------------------------------------------------------------------------
// conv_fused: conv-as-GEMM + LN + FiLM + spatial mean in ONE kernel.
// 1 block per (b,t): tile 64m (spatial tokens) x 512n (channels), K=576, BK=32.
// Chunk swizzle c ^ ((row>>1)&3) keeps BK=32 reads at free 2-way.
__global__ __launch_bounds__(256, 2) void conv_fused(
    const short* __restrict__ xbf, const short* __restrict__ wbf,
    const float* __restrict__ cb, const float* __restrict__ tg,
    const float* __restrict__ tb, const float* __restrict__ gb,
    float* __restrict__ h) {
    __shared__ short As[64 * 32];      // 4 KB
    __shared__ short Bs[512 * 32];     // 32 KB
    __shared__ float redsum[4][64], redss[4][64];
    __shared__ float mu_s[64], inv_s[64];
    int bt = blockIdx.x, b = bt >> 5, t = bt & 31;
    int tid = threadIdx.x;
    int wave = tid >> 6, lane = tid & 63, quad = lane >> 4, l16 = lane & 15;

    // A (im2col) per-thread constants: slot=tid -> row=tid>>2, phys chunk=tid&3
    int rowA = tid >> 2;
    int cA = (tid & 3) ^ ((rowA >> 1) & 3);          // logical chunk
    int hn = rowA >> 3, wn2 = rowA & 7;
    long long baseA = (((long long)(b * 32 + t - 2) * 3) << 12)
                      + (long long)(hn * 8) * 64 + wn2 * 8;

    f32x4 acc[4][8];
    #pragma unroll
    for (int mt = 0; mt < 4; mt++)
        #pragma unroll
        for (int nt = 0; nt < 8; nt++) acc[mt][nt] = (f32x4){0.f, 0.f, 0.f, 0.f};

    for (int k0 = 0; k0 < 576; k0 += 32) {
        // B: 512 rows x 4 chunks = 2048 slots, 8 per thread
        #pragma unroll
        for (int e = 0; e < 8; e++) {
            int s = e * 256 + tid;
            int n = s >> 2;
            int c = (s & 3) ^ ((n >> 1) & 3);
            async16(wbf + (size_t)n * 576 + k0 + c * 8, Bs + s * 8);
        }
        // A: 64 rows x 4 chunks = 256 slots, 1 per thread
        {
            int ks = (k0 >> 3) + cA;                 // 0..71
            int ch = (ks >= 24) + (ks >= 48);
            int r = ks - ch * 24;
            int kt = r >> 3, ph = r & 7;
            short8 v8 = (short8){0, 0, 0, 0, 0, 0, 0, 0};
            if (t + kt >= 2)
                v8 = *(const short8*)(xbf + baseA
                        + ((long long)(kt * 3 + ch) << 12) + ph * 64);
            *(short8*)(As + tid * 8) = v8;
        }
        __syncthreads();
        short8 af[4], bf[8];
        #pragma unroll
        for (int mt = 0; mt < 4; mt++) {
            int row = mt * 16 + l16;
            int pc = quad ^ ((row >> 1) & 3);
            af[mt] = *(const short8*)(As + row * 32 + pc * 8);
        }
        #pragma unroll
        for (int nt = 0; nt < 8; nt++) {
            int row = wave * 128 + nt * 16 + l16;
            int pc = quad ^ ((row >> 1) & 3);
            bf[nt] = *(const short8*)(Bs + row * 32 + pc * 8);
        }
        #pragma unroll
        for (int mt = 0; mt < 4; mt++)
            #pragma unroll
            for (int nt = 0; nt < 8; nt++)
                acc[mt][nt] = __builtin_amdgcn_mfma_f32_16x16x32_bf16(
                    af[mt], bf[nt], acc[mt][nt], 0, 0, 0);
        __syncthreads();
    }

    // epilogue: per-token LN (fp32 accs) + FiLM + spatial mean
    float cbn[8], tgn[8], tbn[8], Gn[8], Ben[8];
    #pragma unroll
    for (int nt = 0; nt < 8; nt++) {
        int n = wave * 128 + nt * 16 + l16;
        cbn[nt] = cb[n]; tgn[nt] = tg[n]; tbn[nt] = tb[n];
        Gn[nt]  = 1.f + 0.5f * gb[bt * 1024 + n];
        Ben[nt] = 0.5f * gb[bt * 1024 + 512 + n];
    }
    #pragma unroll
    for (int mt = 0; mt < 4; mt++)
        #pragma unroll
        for (int reg = 0; reg < 4; reg++) {
            float s = 0.f, ss = 0.f;
            #pragma unroll
            for (int nt = 0; nt < 8; nt++) {
                float v = acc[mt][nt][reg] + cbn[nt];
                s += v; ss += v * v;
            }
            #pragma unroll
            for (int o = 1; o < 16; o <<= 1) {
                s  += __shfl_xor(s, o, 64);
                ss += __shfl_xor(ss, o, 64);
            }
            if (l16 == 0) {
                int m = mt * 16 + quad * 4 + reg;
                redsum[wave][m] = s; redss[wave][m] = ss;
            }
        }
    __syncthreads();
    if (tid < 64) {
        float S  = redsum[0][tid] + redsum[1][tid] + redsum[2][tid] + redsum[3][tid];
        float SS = redss[0][tid] + redss[1][tid] + redss[2][tid] + redss[3][tid];
        float mu = S * (1.f / 512.f);
        float var = SS * (1.f / 512.f) - mu * mu;
        mu_s[tid] = mu; inv_s[tid] = rsqrtf(var + EPS);
    }
    __syncthreads();
    float hacc[8] = {0.f, 0.f, 0.f, 0.f, 0.f, 0.f, 0.f, 0.f};
    #pragma unroll
    for (int mt = 0; mt < 4; mt++)
        #pragma unroll
        for (int reg = 0; reg < 4; reg++) {
            int m = mt * 16 + quad * 4 + reg;
            float mu = mu_s[m], inv = inv_s[m];
            #pragma unroll
            for (int nt = 0; nt < 8; nt++) {
                float v = acc[mt][nt][reg] + cbn[nt];
                hacc[nt] += (v - mu) * inv;
            }
        }
    #pragma unroll
    for (int nt = 0; nt < 8; nt++) {
        hacc[nt] += __shfl_xor(hacc[nt], 16, 64);
        hacc[nt] += __shfl_xor(hacc[nt], 32, 64);
    }
    if (quad == 0)
        #pragma unroll
        for (int nt = 0; nt < 8; nt++) {
            int n = wave * 128 + nt * 16 + l16;
            h[bt * 512 + n] = Gn[nt] * (tgn[nt] * (hacc[nt] * (1.f / 64.f)) + tbn[nt])
                              + Ben[nt];
        }
}

// ---------------------------------------------------------------------------
// attn_fused: one block per (b, head). LN -> kqv GEMM (head's 192 cols) ->
// RoPE -> causal softmax -> PV -> yv bf16.
__global__ __launch_bounds__(256) void attn_fused(
    const float* __restrict__ hsrc, const float* __restrict__ lng,
    const float* __restrict__ lnb, const short* __restrict__ Bw,
    const float* __restrict__ bias, short* __restrict__ yv) {
    __shared__ char smem[57344] __attribute__((aligned(16)));
    __shared__ float mu_s[32], inv_s[32];
    short* As = (short*)smem;                      // 32*512*2 = 32768
    short* Bs = (short*)(smem + 32768);            // 192*64*2 = 24576
    float (*qs)[64] = (float(*)[64])(smem);
    float (*ks)[64] = (float(*)[64])(smem + 8192);
    float (*vs)[64] = (float(*)[64])(smem + 16384);
    float (*qr)[64] = (float(*)[64])(smem + 24576);
    float (*kr)[64] = (float(*)[64])(smem + 32768);
    float (*att)[32] = (float(*)[32])(smem + 40960);
    int blk = blockIdx.x, b = blk >> 3, hh = blk & 7;
    int tid = threadIdx.x;
    int m0 = b * 32;
    {
        int row = tid >> 3, l8 = tid & 7;
        const float* hp = hsrc + (size_t)(m0 + row) * 512 + l8 * 64;
        float s = 0.f, ss = 0.f;
        #pragma unroll
        for (int i = 0; i < 16; i++) {
            float4 v = *(const float4*)(hp + i * 4);
            s += v.x + v.y + v.z + v.w;
            ss += v.x * v.x + v.y * v.y + v.z * v.z + v.w * v.w;
        }
        s += __shfl_xor(s, 1, 64); ss += __shfl_xor(ss, 1, 64);
        s += __shfl_xor(s, 2, 64); ss += __shfl_xor(ss, 2, 64);
        s += __shfl_xor(s, 4, 64); ss += __shfl_xor(ss, 4, 64);
        if (l8 == 0) {
            float mu = s * (1.f / 512.f);
            float var = ss * (1.f / 512.f) - mu * mu;
            mu_s[row] = mu;
            inv_s[row] = rsqrtf(var + EPS);
        }
    }
    __syncthreads();
    #pragma unroll
    for (int e = 0; e < 8; e++) {
        int lc = e * 256 + tid;
        int row = lc >> 6, cc = lc & 63;
        float mu = mu_s[row], inv = inv_s[row];
        const float* hp = hsrc + (size_t)(m0 + row) * 512 + cc * 8;
        float4 a = *(const float4*)hp, b2 = *(const float4*)(hp + 4);
        float4 g0 = *(const float4*)(lng + cc * 8), g1 = *(const float4*)(lng + cc * 8 + 4);
        float4 b0 = *(const float4*)(lnb + cc * 8), b1 = *(const float4*)(lnb + cc * 8 + 4);
        short8 o = {f2bf((a.x - mu) * inv * g0.x + b0.x),
                    f2bf((a.y - mu) * inv * g0.y + b0.y),
                    f2bf((a.z - mu) * inv * g0.z + b0.z),
                    f2bf((a.w - mu) * inv * g0.w + b0.w),
                    f2bf((b2.x - mu) * inv * g1.x + b1.x),
                    f2bf((b2.y - mu) * inv * g1.y + b1.y),
                    f2bf((b2.z - mu) * inv * g1.z + b1.z),
                    f2bf((b2.w - mu) * inv * g1.w + b1.w)};
        *(short8*)(As + (row * 64 + (cc ^ (row & 7))) * 8) = o;
    }
    __syncthreads();
    int wave = tid >> 6, lane = tid & 63, quad = lane >> 4, l16 = lane & 15;
    f32x4 acc[2][3];
    #pragma unroll
    for (int m2 = 0; m2 < 2; m2++)
        #pragma unroll
        for (int g = 0; g < 3; g++) acc[m2][g] = (f32x4){0.f, 0.f, 0.f, 0.f};
    for (int k0 = 0; k0 < 512; k0 += 64) {
        #pragma unroll
        for (int e = 0; e < 6; e++) {
            int p = e * 256 + tid;
            int row = p >> 3, seg = (p & 7) ^ (row & 7);
            int n = ((row >> 6) << 9) + hh * 64 + (row & 63);
            async16(Bw + (size_t)n * 512 + k0 + seg * 8, Bs + p * 8);
        }
        __syncthreads();
        #pragma unroll
        for (int ksub = 0; ksub < 2; ksub++) {
            int ccb = ksub * 4 + quad;
            short8 af[2], bf[3];
            #pragma unroll
            for (int m2 = 0; m2 < 2; m2++) {
                int row = m2 * 16 + l16;
                int cc = (k0 >> 3) + ccb;
                af[m2] = *(const short8*)(As + (row * 64 + (cc ^ (row & 7))) * 8);
            }
            #pragma unroll
            for (int g = 0; g < 3; g++) {
                int row = g * 64 + wave * 16 + l16;
                bf[g] = *(const short8*)(Bs + (row * 8 + (ccb ^ (row & 7))) * 8);
            }
            #pragma unroll
            for (int m2 = 0; m2 < 2; m2++)
                #pragma unroll
                for (int g = 0; g < 3; g++)
                    acc[m2][g] = __builtin_amdgcn_mfma_f32_16x16x32_bf16(
                        af[m2], bf[g], acc[m2][g], 0, 0, 0);
        }
        __syncthreads();
    }
    float bb0 = bias[hh * 64 + wave * 16 + l16];
    float bb1 = bias[512 + hh * 64 + wave * 16 + l16];
    float bb2 = bias[1024 + hh * 64 + wave * 16 + l16];
    int dcol = wave * 16 + l16;
    #pragma unroll
    for (int m2 = 0; m2 < 2; m2++)
        #pragma unroll
        for (int reg = 0; reg < 4; reg++) {
            int tkn = m2 * 16 + quad * 4 + reg;
            ks[tkn][dcol] = acc[m2][0][reg] + bb0;
            qs[tkn][dcol] = acc[m2][1][reg] + bb1;
            vs[tkn][dcol] = acc[m2][2][reg] + bb2;
        }
    __syncthreads();
    const float lnb_c = logf(10000.f) / 32.f;
    for (int idx = tid; idx < 2048; idx += 256) {
        int t = idx >> 6, d = idx & 63;
        int j = d & 31;
        float ang = (float)t * expf(-(float)j * lnb_c);
        float sv = sinf(ang), cv = cosf(ang);
        float qv = qs[t][d], kv = ks[t][d];
        float qo = qs[t][d ^ 32], ko = ks[t][d ^ 32];
        float rq = (d < 32) ? -qo : qo;
        float rk = (d < 32) ? -ko : ko;
        qr[t][d] = qv * cv + rq * sv;
        kr[t][d] = kv * cv + rk * sv;
    }
    __syncthreads();
    #pragma unroll
    for (int l = 0; l < 4; l++) {
        int idx = l * 256 + tid;
        int qt = idx >> 5, kt2 = idx & 31;
        float s;
        if (kt2 > qt) {
            s = -1e30f;
        } else {
            float a = 0.f;
            #pragma unroll
            for (int d = 0; d < 64; d++) a = fmaf(qr[qt][d], kr[kt2][d], a);
            s = a * 0.125f;
        }
        att[qt][kt2] = s;
    }
    __syncthreads();
    if (tid < 32) {
        float m = -1e30f;
        #pragma unroll
        for (int k = 0; k < 32; k++) m = fmaxf(m, att[tid][k]);
        float sum = 0.f;
        #pragma unroll
        for (int k = 0; k < 32; k++) {
            float e = expf(att[tid][k] - m);
            att[tid][k] = e;
            sum += e;
        }
        float inv = 1.f / sum;
        #pragma unroll
        for (int k = 0; k < 32; k++) att[tid][k] *= inv;
    }
    __syncthreads();
    for (int idx = tid; idx < 2048; idx += 256) {
        int t = idx >> 6, d = idx & 63;
        float a = 0.f;
        #pragma unroll
        for (int k = 0; k < 32; k++) a = fmaf(att[t][k], vs[k][d], a);
        yv[(size_t)(b * 32 + t) * 512 + hh * 64 + d] = f2bf(a);
    }
}

// ---------------------------------------------------------------------------
// gemm_ln: LN(h 32-row tile) -> As (full K=512, swizzle), B streamed bf16
// [N][512], BK=128. Tile 32m x 128n. mode 0: fp32 out. mode 1: GELU bf16 out.
__global__ __launch_bounds__(256) void gemm_ln(
    const float* __restrict__ hsrc, const float* __restrict__ lng,
    const float* __restrict__ lnb, const short* __restrict__ Bw,
    const float* __restrict__ bias, int N, int mode,
    float* __restrict__ outf, short* __restrict__ outb) {
    __shared__ short As[32 * 512];
    __shared__ short Bs[128 * 128];
    __shared__ float mu_s[32], inv_s[32];
    int tid = threadIdx.x;
    int m0 = blockIdx.y * 32, n0 = blockIdx.x * 128;
    {
        int row = tid >> 3, l8 = tid & 7;
        const float* hp = hsrc + (size_t)(m0 + row) * 512 + l8 * 64;
        float s = 0.f, ss = 0.f;
        #pragma unroll
        for (int i = 0; i < 16; i++) {
            float4 v = *(const float4*)(hp + i * 4);
            s += v.x + v.y + v.z + v.w;
            ss += v.x * v.x + v.y * v.y + v.z * v.z + v.w * v.w;
        }
        s += __shfl_xor(s, 1, 64); ss += __shfl_xor(ss, 1, 64);
        s += __shfl_xor(s, 2, 64); ss += __shfl_xor(ss, 2, 64);
        s += __shfl_xor(s, 4, 64); ss += __shfl_xor(ss, 4, 64);
        if (l8 == 0) {
            float mu = s * (1.f / 512.f);
            float var = ss * (1.f / 512.f) - mu * mu;
            mu_s[row] = mu;
            inv_s[row] = rsqrtf(var + EPS);
        }
    }
    __syncthreads();
    #pragma unroll
    for (int e = 0; e < 8; e++) {
        int lc = e * 256 + tid;
        int row = lc >> 6, cc = lc & 63;
        float mu = mu_s[row], inv = inv_s[row];
        const float* hp = hsrc + (size_t)(m0 + row) * 512 + cc * 8;
        float4 a = *(const float4*)hp, b = *(const float4*)(hp + 4);
        float4 g0 = *(const float4*)(lng + cc * 8), g1 = *(const float4*)(lng + cc * 8 + 4);
        float4 b0 = *(const float4*)(lnb + cc * 8), b1 = *(const float4*)(lnb + cc * 8 + 4);
        short8 o = {f2bf((a.x - mu) * inv * g0.x + b0.x),
                    f2bf((a.y - mu) * inv * g0.y + b0.y),
                    f2bf((a.z - mu) * inv * g0.z + b0.z),
                    f2bf((a.w - mu) * inv * g0.w + b0.w),
                    f2bf((b.x - mu) * inv * g1.x + b1.x),
                    f2bf((b.y - mu) * inv * g1.y + b1.y),
                    f2bf((b.z - mu) * inv * g1.z + b1.z),
                    f2bf((b.w - mu) * inv * g1.w + b1.w)};
        *(short8*)(As + (row * 64 + (cc ^ (row & 7))) * 8) = o;
    }
    __syncthreads();
    int wave = tid >> 6, lane = tid & 63, quad = lane >> 4, l16 = lane & 15;
    f32x4 acc[2][2];
    #pragma unroll
    for (int a2 = 0; a2 < 2; a2++)
        #pragma unroll
        for (int b2 = 0; b2 < 2; b2++) acc[a2][b2] = (f32x4){0.f, 0.f, 0.f, 0.f};
    for (int k0 = 0; k0 < 512; k0 += 128) {
        #pragma unroll
        for (int e = 0; e < 8; e++) {
            int p = e * 256 + tid;
            int row = p >> 4, seg = (p & 15) ^ (row & 15);
            async16(Bw + (size_t)(n0 + row) * 512 + k0 + seg * 8, Bs + p * 8);
        }
        __syncthreads();
        #pragma unroll
        for (int ksub = 0; ksub < 4; ksub++) {
            int ccb = ksub * 4 + quad;
            short8 af[2], bf[2];
            #pragma unroll
            for (int m2 = 0; m2 < 2; m2++) {
                int row = m2 * 16 + l16;
                int cc = (k0 >> 3) + ccb;
                af[m2] = *(const short8*)(As + (row * 64 + (cc ^ (row & 7))) * 8);
            }
            #pragma unroll
            for (int n2 = 0; n2 < 2; n2++) {
                int row = wave * 32 + n2 * 16 + l16;
                bf[n2] = *(const short8*)(Bs + (row * 16 + (ccb ^ (row & 15))) * 8);
            }
            #pragma unroll
            for (int m2 = 0; m2 < 2; m2++)
                #pragma unroll
                for (int n2 = 0; n2 < 2; n2++)
                    acc[m2][n2] = __builtin_amdgcn_mfma_f32_16x16x32_bf16(
                        af[m2], bf[n2], acc[m2][n2], 0, 0, 0);
        }
        __syncthreads();
    }
    #pragma unroll
    for (int m2 = 0; m2 < 2; m2++)
        #pragma unroll
        for (int n2 = 0; n2 < 2; n2++)
            #pragma unroll
            for (int reg = 0; reg < 4; reg++) {
                int m = m0 + m2 * 16 + quad * 4 + reg;
                int n = n0 + wave * 32 + n2 * 16 + l16;
                float v = acc[m2][n2][reg] + bias[n];
                if (mode == 1) {
                    v = 0.5f * v * (1.f + erff(v * 0.70710678118f));
                    outb[(size_t)m * N + n] = f2bf(v);
                } else {
                    outf[(size_t)m * N + n] = v;
                }
            }
}

// ---------------------------------------------------------------------------
// gemm_res (split-K): A[M][K] bf16, B[N][K] bf16, BK=128. Tile 32m x 64n.
// blockIdx.z = K-split slice of size Ks. h[m][n] atomicAdd rs*(acc [+bias z=0]).
__global__ __launch_bounds__(256) void gemm_res(
    const short* __restrict__ Ag, const short* __restrict__ Bw,
    const float* __restrict__ bias, const float* __restrict__ rsPtr,
    float* __restrict__ hm, int K, int Ks) {
    __shared__ short As[32 * 128];
    __shared__ short Bs[64 * 128];
    int tid = threadIdx.x;
    int m0 = blockIdx.y * 32, n0 = blockIdx.x * 64;
    int kbase = blockIdx.z * Ks;
    int wave = tid >> 6, lane = tid & 63, quad = lane >> 4, l16 = lane & 15;
    f32x4 acc[2];
    acc[0] = (f32x4){0.f, 0.f, 0.f, 0.f};
    acc[1] = (f32x4){0.f, 0.f, 0.f, 0.f};
    for (int k0 = kbase; k0 < kbase + Ks; k0 += 128) {
        #pragma unroll
        for (int e = 0; e < 2; e++) {
            int p = e * 256 + tid;
            int row = p >> 4, seg = (p & 15) ^ (row & 15);
            async16(Ag + (size_t)(m0 + row) * K + k0 + seg * 8, As + p * 8);
        }
        #pragma unroll
        for (int e = 0; e < 4; e++) {
            int p = e * 256 + tid;
            int row = p >> 4, seg = (p & 15) ^ (row & 15);
            async16(Bw + (size_t)(n0 + row) * K + k0 + seg * 8, Bs + p * 8);
        }
        __syncthreads();
        #pragma unroll
        for (int ksub = 0; ksub < 4; ksub++) {
            int ccb = ksub * 4 + quad;
            short8 bf;
            {
                int row = wave * 16 + l16;
                bf = *(const short8*)(Bs + (row * 16 + (ccb ^ (row & 15))) * 8);
            }
            #pragma unroll
            for (int m2 = 0; m2 < 2; m2++) {
                int row = m2 * 16 + l16;
                short8 af = *(const short8*)(As + (row * 16 + (ccb ^ (row & 15))) * 8);
                acc[m2] = __builtin_amdgcn_mfma_f32_16x16x32_bf16(af, bf, acc[m2], 0, 0, 0);
            }
        }
        __syncthreads();
    }
    float rsv = *rsPtr;
    bool addb = (blockIdx.z == 0);
    #pragma unroll
    for (int m2 = 0; m2 < 2; m2++)
        #pragma unroll
        for (int reg = 0; reg < 4; reg++) {
            int m = m0 + m2 * 16 + quad * 4 + reg;
            int n = n0 + wave * 16 + l16;
            float v = acc[m2][reg] + (addb ? bias[n] : 0.f);
            atomicAdd(&hm[(size_t)m * 512 + n], rsv * v);
        }
}

// ---------------------------------------------------------------------------
__global__ __launch_bounds__(256) void head_kernel(
    const float* __restrict__ h, const float* __restrict__ g,
    const float* __restrict__ bb, const float* __restrict__ w,
    const float* __restrict__ bias0, float* __restrict__ out) {
    __shared__ float red[8];
    int token = blockIdx.x, tid = threadIdx.x;
    float v0 = h[token * 512 + tid], v1 = h[token * 512 + tid + 256];
    float s  = block_reduce_sum_256(v0 + v1, red);
    float ss = block_reduce_sum_256(v0 * v0 + v1 * v1, red);
    float mu = s * (1.f / 512.f);
    float var = ss * (1.f / 512.f) - mu * mu;
    float inv = rsqrtf(var + EPS);
    float n0 = (v0 - mu) * inv * g[tid] + bb[tid];
    float n1 = (v1 - mu) * inv * g[tid + 256] + bb[tid + 256];
    float dot = block_reduce_sum_256(n0 * w[tid] + n1 * w[tid + 256], red);
    if (tid == 0) out[token] = dot + bias0[0];
}

// ---------------------------------------------------------------------------
extern "C" void kernel_launch(void* const* d_in, const int* in_sizes, int n_in,
                              void* d_out, int out_size, void* d_ws, size_t ws_size,
                              hipStream_t stream) {
    const float* x       = (const float*)d_in[0];
    const float* z       = (const float*)d_in[1];
    const float* conv_w  = (const float*)d_in[2];
    const float* conv_b  = (const float*)d_in[3];
    const float* tok_g   = (const float*)d_in[4];
    const float* tok_b   = (const float*)d_in[5];
    const float* film_w  = (const float*)d_in[6];
    const float* film_b  = (const float*)d_in[7];
    const float* ln1_g   = (const float*)d_in[8];
    const float* ln1_b   = (const float*)d_in[9];
    const float* kqv_w   = (const float*)d_in[10];
    const float* kqv_b   = (const float*)d_in[11];
    const float* proj_w  = (const float*)d_in[12];
    const float* proj_b  = (const float*)d_in[13];
    const float* ln2_g   = (const float*)d_in[14];
    const float* ln2_b   = (const float*)d_in[15];
    const float* mlp_w1  = (const float*)d_in[16];
    const float* mlp_b1  = (const float*)d_in[17];
    const float* mlp_w2  = (const float*)d_in[18];
    const float* mlp_b2  = (const float*)d_in[19];
    const float* rs_attn = (const float*)d_in[20];
    const float* rs_mlp  = (const float*)d_in[21];
    const float* head_g  = (const float*)d_in[22];
    const float* head_b  = (const float*)d_in[23];
    const float* head_w  = (const float*)d_in[24];
    const float* head_bs = (const float*)d_in[25];
    float* out = (float*)d_out;

    float* ws = (float*)d_ws;
    float* gb   = ws;                  // 524288 f
    float* h    = gb + 524288;         // 262144 f
    short* sb = (short*)(h + 262144);
    short* wbf   = sb;                 // 294912
    short* kqvT  = wbf   + 294912;     // 4718592
    short* projT = kqvT  + 4718592;    // 1572864
    short* mlp1T = projT + 1572864;    // 6291456
    short* mlp2T = mlp1T + 6291456;    // 6291456
    short* yvb   = mlp2T + 6291456;    // 262144
    short* mbuf  = yvb   + 262144;     // 1048576
    short* xbf   = mbuf  + 1048576;    // 6291456

    prep_misc<<<4736, 256, 0, stream>>>(z, film_w, film_b, gb, conv_w, wbf, x, xbf);
    prep_tcast<<<18432, 256, 0, stream>>>(kqv_w, kqvT, proj_w, projT,
                                          mlp_w1, mlp1T, mlp_w2, mlp2T);

    conv_fused<<<512, 256, 0, stream>>>(xbf, wbf, conv_b, tok_g, tok_b, gb, h);

    for (int i = 0; i < 6; i++) {
        attn_fused<<<128, 256, 0, stream>>>(
            h, ln1_g + i * 512, ln1_b + i * 512,
            kqvT + (size_t)i * 1536 * 512, kqv_b + i * 1536, yvb);
        gemm_res<<<dim3(8, 16, 2), 256, 0, stream>>>(
            yvb, projT + (size_t)i * 512 * 512, proj_b + i * 512,
            rs_attn + i, h, 512, 256);
        gemm_ln<<<dim3(16, 16), 256, 0, stream>>>(
            h, ln2_g + i * 512, ln2_b + i * 512,
            mlp1T + (size_t)i * 2048 * 512, mlp_b1 + i * 2048,
            2048, 1, nullptr, mbuf);
        gemm_res<<<dim3(8, 16, 4), 256, 0, stream>>>(
            mbuf, mlp2T + (size_t)i * 512 * 2048, mlp_b2 + i * 512,
            rs_mlp + i, h, 2048, 512);
    }

    head_kernel<<<512, 256, 0, stream>>>(h, head_g, head_b, head_w, head_bs, out);
}

// Round 8
// 465.562 us; speedup vs baseline: 3.0630x; 1.0978x over previous
//
#include <hip/hip_runtime.h>
#include <math.h>

#define EPS 1e-5f

typedef __attribute__((ext_vector_type(8))) short short8;
typedef __attribute__((ext_vector_type(4))) float f32x4;

__device__ __forceinline__ short f2bf(float f) {
    unsigned u = __float_as_uint(f);
    u += 0x7fffu + ((u >> 16) & 1u);
    return (short)(u >> 16);
}
__device__ __forceinline__ float bf2f(short s) {
    return __uint_as_float(((unsigned)(unsigned short)s) << 16);
}
__device__ __forceinline__ void async16(const void* g, void* l) {
    __builtin_amdgcn_global_load_lds(
        (const __attribute__((address_space(1))) unsigned*)g,
        (__attribute__((address_space(3))) unsigned*)l, 16, 0, 0);
}

// ---------------------------------------------------------------------------
__device__ __forceinline__ float block_reduce_sum_256(float v, float* red) {
    #pragma unroll
    for (int o = 32; o > 0; o >>= 1) v += __shfl_down(v, o, 64);
    __syncthreads();
    if ((threadIdx.x & 63) == 0) red[threadIdx.x >> 6] = v;
    __syncthreads();
    return red[0] + red[1] + red[2] + red[3];
}

// ---------------------------------------------------------------------------
// prep_all: [0,512) film | [512,1664) conv_w cast | [1664,4736) x cast |
// [4736,4740) rope table | [4740,23172) weight transpose+cast.
__global__ __launch_bounds__(256) void prep_all(
    const float* __restrict__ z, const float* __restrict__ fw,
    const float* __restrict__ fb, float* __restrict__ gb,
    const float* __restrict__ conv_w, short* __restrict__ wbf,
    const float* __restrict__ x, short* __restrict__ xbf,
    float* __restrict__ ropeS, float* __restrict__ ropeC,
    const float* __restrict__ kqv_w, short* __restrict__ kqvT,
    const float* __restrict__ proj_w, short* __restrict__ projT,
    const float* __restrict__ mlp_w1, short* __restrict__ mlp1T,
    const float* __restrict__ mlp_w2, short* __restrict__ mlp2T) {
    int bi = blockIdx.x, tid = threadIdx.x;
    if (bi < 512) {
        __shared__ float zs[32];
        if (tid < 32) zs[tid] = z[bi * 32 + tid];
        __syncthreads();
        for (int j = tid; j < 1024; j += 256) {
            float acc = fb[j];
            #pragma unroll
            for (int k = 0; k < 32; k++) acc = fmaf(zs[k], fw[k * 1024 + j], acc);
            gb[bi * 1024 + j] = acc;
        }
        return;
    }
    if (bi < 1664) {
        int i = (bi - 512) * 256 + tid;
        wbf[i] = f2bf(conv_w[i]);
        return;
    }
    if (bi < 4736) {
        int i = (bi - 1664) * 256 + tid;
        float4 a = *(const float4*)(x + (size_t)i * 8);
        float4 b = *(const float4*)(x + (size_t)i * 8 + 4);
        short8 o = {f2bf(a.x), f2bf(a.y), f2bf(a.z), f2bf(a.w),
                    f2bf(b.x), f2bf(b.y), f2bf(b.z), f2bf(b.w)};
        *(short8*)(xbf + (size_t)i * 8) = o;
        return;
    }
    if (bi < 4740) {
        int idx = (bi - 4736) * 256 + tid;        // 1024 entries
        if (idx < 1024) {
            int t = idx >> 5, j = idx & 31;
            float ang = (float)t * expf(-(float)j * (logf(10000.f) / 32.f));
            ropeS[idx] = sinf(ang);
            ropeC[idx] = cosf(ang);
        }
        return;
    }
    // weight transpose+cast
    __shared__ float tile[32][33];
    int rel0 = bi - 4740;
    const float* src; short* dst; int NT, K, N, rel;
    if (rel0 < 4608)       { src = kqv_w;  dst = kqvT;  NT = 48; K = 512;  N = 1536; rel = rel0; }
    else if (rel0 < 6144)  { src = proj_w; dst = projT; NT = 16; K = 512;  N = 512;  rel = rel0 - 4608; }
    else if (rel0 < 12288) { src = mlp_w1; dst = mlp1T; NT = 64; K = 512;  N = 2048; rel = rel0 - 6144; }
    else                   { src = mlp_w2; dst = mlp2T; NT = 16; K = 2048; N = 512;  rel = rel0 - 12288; }
    int per = NT * (K / 32);
    int layer = rel / per, r2 = rel - layer * per;
    int nt = r2 % NT, kt = r2 / NT;
    src += (size_t)layer * K * N;
    dst += (size_t)layer * N * K;
    int n0 = nt * 32, k0 = kt * 32;
    int lx = tid & 31, ly = tid >> 5;
    #pragma unroll
    for (int i = 0; i < 32; i += 8)
        tile[ly + i][lx] = src[(size_t)(k0 + ly + i) * N + n0 + lx];
    __syncthreads();
    int kp = tid & 15, nn = tid >> 4;
    #pragma unroll
    for (int i = 0; i < 2; i++) {
        int row = nn + i * 16;
        short2 o = {f2bf(tile[kp * 2][row]), f2bf(tile[kp * 2 + 1][row])};
        *(short2*)(dst + (size_t)(n0 + row) * K + k0 + kp * 2) = o;
    }
}

// ---------------------------------------------------------------------------
// conv_fused: conv-as-GEMM + LN + FiLM + spatial mean in ONE kernel.
__global__ __launch_bounds__(256, 2) void conv_fused(
    const short* __restrict__ xbf, const short* __restrict__ wbf,
    const float* __restrict__ cb, const float* __restrict__ tg,
    const float* __restrict__ tb, const float* __restrict__ gb,
    float* __restrict__ h) {
    __shared__ short As[64 * 32];
    __shared__ short Bs[512 * 32];
    __shared__ float redsum[4][64], redss[4][64];
    __shared__ float mu_s[64], inv_s[64];
    int bt = blockIdx.x, b = bt >> 5, t = bt & 31;
    int tid = threadIdx.x;
    int wave = tid >> 6, lane = tid & 63, quad = lane >> 4, l16 = lane & 15;

    int rowA = tid >> 2;
    int cA = (tid & 3) ^ ((rowA >> 1) & 3);
    int hn = rowA >> 3, wn2 = rowA & 7;
    long long baseA = (((long long)(b * 32 + t - 2) * 3) << 12)
                      + (long long)(hn * 8) * 64 + wn2 * 8;

    f32x4 acc[4][8];
    #pragma unroll
    for (int mt = 0; mt < 4; mt++)
        #pragma unroll
        for (int nt = 0; nt < 8; nt++) acc[mt][nt] = (f32x4){0.f, 0.f, 0.f, 0.f};

    for (int k0 = 0; k0 < 576; k0 += 32) {
        #pragma unroll
        for (int e = 0; e < 8; e++) {
            int s = e * 256 + tid;
            int n = s >> 2;
            int c = (s & 3) ^ ((n >> 1) & 3);
            async16(wbf + (size_t)n * 576 + k0 + c * 8, Bs + s * 8);
        }
        {
            int ks = (k0 >> 3) + cA;
            int ch = (ks >= 24) + (ks >= 48);
            int r = ks - ch * 24;
            int kt = r >> 3, ph = r & 7;
            short8 v8 = (short8){0, 0, 0, 0, 0, 0, 0, 0};
            if (t + kt >= 2)
                v8 = *(const short8*)(xbf + baseA
                        + ((long long)(kt * 3 + ch) << 12) + ph * 64);
            *(short8*)(As + tid * 8) = v8;
        }
        __syncthreads();
        short8 af[4], bf[8];
        #pragma unroll
        for (int mt = 0; mt < 4; mt++) {
            int row = mt * 16 + l16;
            int pc = quad ^ ((row >> 1) & 3);
            af[mt] = *(const short8*)(As + row * 32 + pc * 8);
        }
        #pragma unroll
        for (int nt = 0; nt < 8; nt++) {
            int row = wave * 128 + nt * 16 + l16;
            int pc = quad ^ ((row >> 1) & 3);
            bf[nt] = *(const short8*)(Bs + row * 32 + pc * 8);
        }
        #pragma unroll
        for (int mt = 0; mt < 4; mt++)
            #pragma unroll
            for (int nt = 0; nt < 8; nt++)
                acc[mt][nt] = __builtin_amdgcn_mfma_f32_16x16x32_bf16(
                    af[mt], bf[nt], acc[mt][nt], 0, 0, 0);
        __syncthreads();
    }

    float cbn[8], tgn[8], tbn[8], Gn[8], Ben[8];
    #pragma unroll
    for (int nt = 0; nt < 8; nt++) {
        int n = wave * 128 + nt * 16 + l16;
        cbn[nt] = cb[n]; tgn[nt] = tg[n]; tbn[nt] = tb[n];
        Gn[nt]  = 1.f + 0.5f * gb[bt * 1024 + n];
        Ben[nt] = 0.5f * gb[bt * 1024 + 512 + n];
    }
    #pragma unroll
    for (int mt = 0; mt < 4; mt++)
        #pragma unroll
        for (int reg = 0; reg < 4; reg++) {
            float s = 0.f, ss = 0.f;
            #pragma unroll
            for (int nt = 0; nt < 8; nt++) {
                float v = acc[mt][nt][reg] + cbn[nt];
                s += v; ss += v * v;
            }
            #pragma unroll
            for (int o = 1; o < 16; o <<= 1) {
                s  += __shfl_xor(s, o, 64);
                ss += __shfl_xor(ss, o, 64);
            }
            if (l16 == 0) {
                int m = mt * 16 + quad * 4 + reg;
                redsum[wave][m] = s; redss[wave][m] = ss;
            }
        }
    __syncthreads();
    if (tid < 64) {
        float S  = redsum[0][tid] + redsum[1][tid] + redsum[2][tid] + redsum[3][tid];
        float SS = redss[0][tid] + redss[1][tid] + redss[2][tid] + redss[3][tid];
        float mu = S * (1.f / 512.f);
        float var = SS * (1.f / 512.f) - mu * mu;
        mu_s[tid] = mu; inv_s[tid] = rsqrtf(var + EPS);
    }
    __syncthreads();
    float hacc[8] = {0.f, 0.f, 0.f, 0.f, 0.f, 0.f, 0.f, 0.f};
    #pragma unroll
    for (int mt = 0; mt < 4; mt++)
        #pragma unroll
        for (int reg = 0; reg < 4; reg++) {
            int m = mt * 16 + quad * 4 + reg;
            float mu = mu_s[m], inv = inv_s[m];
            #pragma unroll
            for (int nt = 0; nt < 8; nt++) {
                float v = acc[mt][nt][reg] + cbn[nt];
                hacc[nt] += (v - mu) * inv;
            }
        }
    #pragma unroll
    for (int nt = 0; nt < 8; nt++) {
        hacc[nt] += __shfl_xor(hacc[nt], 16, 64);
        hacc[nt] += __shfl_xor(hacc[nt], 32, 64);
    }
    if (quad == 0)
        #pragma unroll
        for (int nt = 0; nt < 8; nt++) {
            int n = wave * 128 + nt * 16 + l16;
            h[bt * 512 + n] = Gn[nt] * (tgn[nt] * (hacc[nt] * (1.f / 64.f)) + tbn[nt])
                              + Ben[nt];
        }
}

// ---------------------------------------------------------------------------
// attn_fused: one block per (b, head). LN -> kqv GEMM (head's 192 cols) ->
// RoPE (table) -> MFMA QK^T -> parallel softmax -> MFMA PV -> yv bf16.
__global__ __launch_bounds__(256) void attn_fused(
    const float* __restrict__ hsrc, const float* __restrict__ lng,
    const float* __restrict__ lnb, const short* __restrict__ Bw,
    const float* __restrict__ bias, const float* __restrict__ ropeS,
    const float* __restrict__ ropeC, short* __restrict__ yv) {
    __shared__ char smem[57344] __attribute__((aligned(16)));
    __shared__ float mu_s[32], inv_s[32];
    short* As = (short*)smem;                      // GEMM phase: 32K
    short* Bs = (short*)(smem + 32768);            // GEMM phase: 24K
    // attention phase overlays:
    float (*qsf)[64] = (float(*)[64])(smem);               // 8K @0
    float (*ksf)[64] = (float(*)[64])(smem + 8192);        // 8K @8192
    short* vT  = (short*)(smem + 16384);                    // 4K  [d][t] swizzled
    short* qrb = (short*)(smem + 20480);                    // 4K  [t][d] swizzled
    short* krb = (short*)(smem + 24576);                    // 4K
    float (*att)[33] = (float(*)[33])(smem + 28672);        // 4224
    short* pA  = (short*)(smem + 36864);                    // 2K  [t][k]
    int blk = blockIdx.x, b = blk >> 3, hh = blk & 7;
    int tid = threadIdx.x;
    int m0 = b * 32;
    // LN pass 1
    {
        int row = tid >> 3, l8 = tid & 7;
        const float* hp = hsrc + (size_t)(m0 + row) * 512 + l8 * 64;
        float s = 0.f, ss = 0.f;
        #pragma unroll
        for (int i = 0; i < 16; i++) {
            float4 v = *(const float4*)(hp + i * 4);
            s += v.x + v.y + v.z + v.w;
            ss += v.x * v.x + v.y * v.y + v.z * v.z + v.w * v.w;
        }
        s += __shfl_xor(s, 1, 64); ss += __shfl_xor(ss, 1, 64);
        s += __shfl_xor(s, 2, 64); ss += __shfl_xor(ss, 2, 64);
        s += __shfl_xor(s, 4, 64); ss += __shfl_xor(ss, 4, 64);
        if (l8 == 0) {
            float mu = s * (1.f / 512.f);
            float var = ss * (1.f / 512.f) - mu * mu;
            mu_s[row] = mu;
            inv_s[row] = rsqrtf(var + EPS);
        }
    }
    __syncthreads();
    // LN pass 2 -> As
    #pragma unroll
    for (int e = 0; e < 8; e++) {
        int lc = e * 256 + tid;
        int row = lc >> 6, cc = lc & 63;
        float mu = mu_s[row], inv = inv_s[row];
        const float* hp = hsrc + (size_t)(m0 + row) * 512 + cc * 8;
        float4 a = *(const float4*)hp, b2 = *(const float4*)(hp + 4);
        float4 g0 = *(const float4*)(lng + cc * 8), g1 = *(const float4*)(lng + cc * 8 + 4);
        float4 b0 = *(const float4*)(lnb + cc * 8), b1 = *(const float4*)(lnb + cc * 8 + 4);
        short8 o = {f2bf((a.x - mu) * inv * g0.x + b0.x),
                    f2bf((a.y - mu) * inv * g0.y + b0.y),
                    f2bf((a.z - mu) * inv * g0.z + b0.z),
                    f2bf((a.w - mu) * inv * g0.w + b0.w),
                    f2bf((b2.x - mu) * inv * g1.x + b1.x),
                    f2bf((b2.y - mu) * inv * g1.y + b1.y),
                    f2bf((b2.z - mu) * inv * g1.z + b1.z),
                    f2bf((b2.w - mu) * inv * g1.w + b1.w)};
        *(short8*)(As + (row * 64 + (cc ^ (row & 7))) * 8) = o;
    }
    __syncthreads();
    int wave = tid >> 6, lane = tid & 63, quad = lane >> 4, l16 = lane & 15;
    f32x4 acc[2][3];
    #pragma unroll
    for (int m2 = 0; m2 < 2; m2++)
        #pragma unroll
        for (int g = 0; g < 3; g++) acc[m2][g] = (f32x4){0.f, 0.f, 0.f, 0.f};
    for (int k0 = 0; k0 < 512; k0 += 64) {
        #pragma unroll
        for (int e = 0; e < 6; e++) {
            int p = e * 256 + tid;
            int row = p >> 3, seg = (p & 7) ^ (row & 7);
            int n = ((row >> 6) << 9) + hh * 64 + (row & 63);
            async16(Bw + (size_t)n * 512 + k0 + seg * 8, Bs + p * 8);
        }
        __syncthreads();
        #pragma unroll
        for (int ksub = 0; ksub < 2; ksub++) {
            int ccb = ksub * 4 + quad;
            short8 af[2], bf[3];
            #pragma unroll
            for (int m2 = 0; m2 < 2; m2++) {
                int row = m2 * 16 + l16;
                int cc = (k0 >> 3) + ccb;
                af[m2] = *(const short8*)(As + (row * 64 + (cc ^ (row & 7))) * 8);
            }
            #pragma unroll
            for (int g = 0; g < 3; g++) {
                int row = g * 64 + wave * 16 + l16;
                bf[g] = *(const short8*)(Bs + (row * 8 + (ccb ^ (row & 7))) * 8);
            }
            #pragma unroll
            for (int m2 = 0; m2 < 2; m2++)
                #pragma unroll
                for (int g = 0; g < 3; g++)
                    acc[m2][g] = __builtin_amdgcn_mfma_f32_16x16x32_bf16(
                        af[m2], bf[g], acc[m2][g], 0, 0, 0);
        }
        __syncthreads();
    }
    // phase 1: k,q fp32 -> LDS; v -> vT bf16 (chunk-swizzled)
    float bb0 = bias[hh * 64 + wave * 16 + l16];
    float bb1 = bias[512 + hh * 64 + wave * 16 + l16];
    float bb2 = bias[1024 + hh * 64 + wave * 16 + l16];
    int dcol = wave * 16 + l16;
    #pragma unroll
    for (int m2 = 0; m2 < 2; m2++)
        #pragma unroll
        for (int reg = 0; reg < 4; reg++) {
            int tkn = m2 * 16 + quad * 4 + reg;
            ksf[tkn][dcol] = acc[m2][0][reg] + bb0;
            qsf[tkn][dcol] = acc[m2][1][reg] + bb1;
            vT[dcol * 32 + (((tkn >> 3) ^ (dcol & 3)) << 3) + (tkn & 7)]
                = f2bf(acc[m2][2][reg] + bb2);
        }
    __syncthreads();
    // phase 2: RoPE (table) -> qrb/krb bf16 (chunk-swizzled rows of 64)
    #pragma unroll
    for (int e = 0; e < 8; e++) {
        int idx = e * 256 + tid;
        int t = idx >> 6, d = idx & 63, j = d & 31;
        float sv = ropeS[t * 32 + j], cv = ropeC[t * 32 + j];
        float qv = qsf[t][d], kv = ksf[t][d];
        float qo = qsf[t][d ^ 32], ko = ksf[t][d ^ 32];
        float rq = (d < 32) ? -qo : qo;
        float rk = (d < 32) ? -ko : ko;
        int addr = t * 64 + (((d >> 3) ^ (t & 7)) << 3) + (d & 7);
        qrb[addr] = f2bf(qv * cv + rq * sv);
        krb[addr] = f2bf(kv * cv + rk * sv);
    }
    __syncthreads();
    // phase 3: QK^T via MFMA (wave -> score tile (mw,nw)), mask+scale -> att
    int mw = wave & 1, nw = wave >> 1;
    {
        f32x4 sc = (f32x4){0.f, 0.f, 0.f, 0.f};
        #pragma unroll
        for (int kc = 0; kc < 2; kc++) {
            int rq = mw * 16 + l16;
            int rk = nw * 16 + l16;
            short8 aq = *(const short8*)(qrb + rq * 64 + ((((kc << 2) + quad) ^ (rq & 7)) << 3));
            short8 bk = *(const short8*)(krb + rk * 64 + ((((kc << 2) + quad) ^ (rk & 7)) << 3));
            sc = __builtin_amdgcn_mfma_f32_16x16x32_bf16(aq, bk, sc, 0, 0, 0);
        }
        #pragma unroll
        for (int reg = 0; reg < 4; reg++) {
            int qt = mw * 16 + quad * 4 + reg;
            int kt = nw * 16 + l16;
            att[qt][kt] = (kt > qt) ? -1e30f : sc[reg] * 0.125f;
        }
    }
    __syncthreads();
    // phase 4: softmax, 8 lanes per row, 4 cols each -> pA bf16 [t][k]
    {
        int row = tid >> 3, g = tid & 7;
        float v0 = att[row][g * 4], v1 = att[row][g * 4 + 1];
        float v2 = att[row][g * 4 + 2], v3 = att[row][g * 4 + 3];
        float mx = fmaxf(fmaxf(v0, v1), fmaxf(v2, v3));
        mx = fmaxf(mx, __shfl_xor(mx, 1, 64));
        mx = fmaxf(mx, __shfl_xor(mx, 2, 64));
        mx = fmaxf(mx, __shfl_xor(mx, 4, 64));
        float e0 = expf(v0 - mx), e1 = expf(v1 - mx);
        float e2 = expf(v2 - mx), e3 = expf(v3 - mx);
        float s = e0 + e1 + e2 + e3;
        s += __shfl_xor(s, 1, 64);
        s += __shfl_xor(s, 2, 64);
        s += __shfl_xor(s, 4, 64);
        float inv = 1.f / s;
        short* pp = pA + row * 32 + g * 4;
        pp[0] = f2bf(e0 * inv); pp[1] = f2bf(e1 * inv);
        pp[2] = f2bf(e2 * inv); pp[3] = f2bf(e3 * inv);
    }
    __syncthreads();
    // phase 5: PV via MFMA. wave -> m-tile (wave&1), n-tiles (wave>>1)*2+{0,1}
    {
        int rp = mw * 16 + l16;
        short8 ap = *(const short8*)(pA + rp * 32 + quad * 8);
        #pragma unroll
        for (int i = 0; i < 2; i++) {
            int nt = (wave >> 1) * 2 + i;
            int rv = nt * 16 + l16;
            short8 bv = *(const short8*)(vT + rv * 32 + (((quad ^ (rv & 3))) << 3));
            f32x4 o = (f32x4){0.f, 0.f, 0.f, 0.f};
            o = __builtin_amdgcn_mfma_f32_16x16x32_bf16(ap, bv, o, 0, 0, 0);
            #pragma unroll
            for (int reg = 0; reg < 4; reg++) {
                int t = mw * 16 + quad * 4 + reg;
                int d = nt * 16 + l16;
                yv[(size_t)(b * 32 + t) * 512 + hh * 64 + d] = f2bf(o[reg]);
            }
        }
    }
}

// ---------------------------------------------------------------------------
// gemm_ln: LN(h 32-row tile) -> As (full K=512, swizzle), B streamed bf16
// [N][512], BK=128. Tile 32m x 128n. mode 0: fp32 out. mode 1: GELU bf16 out.
__global__ __launch_bounds__(256) void gemm_ln(
    const float* __restrict__ hsrc, const float* __restrict__ lng,
    const float* __restrict__ lnb, const short* __restrict__ Bw,
    const float* __restrict__ bias, int N, int mode,
    float* __restrict__ outf, short* __restrict__ outb) {
    __shared__ short As[32 * 512];
    __shared__ short Bs[128 * 128];
    __shared__ float mu_s[32], inv_s[32];
    int tid = threadIdx.x;
    int m0 = blockIdx.y * 32, n0 = blockIdx.x * 128;
    {
        int row = tid >> 3, l8 = tid & 7;
        const float* hp = hsrc + (size_t)(m0 + row) * 512 + l8 * 64;
        float s = 0.f, ss = 0.f;
        #pragma unroll
        for (int i = 0; i < 16; i++) {
            float4 v = *(const float4*)(hp + i * 4);
            s += v.x + v.y + v.z + v.w;
            ss += v.x * v.x + v.y * v.y + v.z * v.z + v.w * v.w;
        }
        s += __shfl_xor(s, 1, 64); ss += __shfl_xor(ss, 1, 64);
        s += __shfl_xor(s, 2, 64); ss += __shfl_xor(ss, 2, 64);
        s += __shfl_xor(s, 4, 64); ss += __shfl_xor(ss, 4, 64);
        if (l8 == 0) {
            float mu = s * (1.f / 512.f);
            float var = ss * (1.f / 512.f) - mu * mu;
            mu_s[row] = mu;
            inv_s[row] = rsqrtf(var + EPS);
        }
    }
    __syncthreads();
    #pragma unroll
    for (int e = 0; e < 8; e++) {
        int lc = e * 256 + tid;
        int row = lc >> 6, cc = lc & 63;
        float mu = mu_s[row], inv = inv_s[row];
        const float* hp = hsrc + (size_t)(m0 + row) * 512 + cc * 8;
        float4 a = *(const float4*)hp, b = *(const float4*)(hp + 4);
        float4 g0 = *(const float4*)(lng + cc * 8), g1 = *(const float4*)(lng + cc * 8 + 4);
        float4 b0 = *(const float4*)(lnb + cc * 8), b1 = *(const float4*)(lnb + cc * 8 + 4);
        short8 o = {f2bf((a.x - mu) * inv * g0.x + b0.x),
                    f2bf((a.y - mu) * inv * g0.y + b0.y),
                    f2bf((a.z - mu) * inv * g0.z + b0.z),
                    f2bf((a.w - mu) * inv * g0.w + b0.w),
                    f2bf((b.x - mu) * inv * g1.x + b1.x),
                    f2bf((b.y - mu) * inv * g1.y + b1.y),
                    f2bf((b.z - mu) * inv * g1.z + b1.z),
                    f2bf((b.w - mu) * inv * g1.w + b1.w)};
        *(short8*)(As + (row * 64 + (cc ^ (row & 7))) * 8) = o;
    }
    __syncthreads();
    int wave = tid >> 6, lane = tid & 63, quad = lane >> 4, l16 = lane & 15;
    f32x4 acc[2][2];
    #pragma unroll
    for (int a2 = 0; a2 < 2; a2++)
        #pragma unroll
        for (int b2 = 0; b2 < 2; b2++) acc[a2][b2] = (f32x4){0.f, 0.f, 0.f, 0.f};
    for (int k0 = 0; k0 < 512; k0 += 128) {
        #pragma unroll
        for (int e = 0; e < 8; e++) {
            int p = e * 256 + tid;
            int row = p >> 4, seg = (p & 15) ^ (row & 15);
            async16(Bw + (size_t)(n0 + row) * 512 + k0 + seg * 8, Bs + p * 8);
        }
        __syncthreads();
        #pragma unroll
        for (int ksub = 0; ksub < 4; ksub++) {
            int ccb = ksub * 4 + quad;
            short8 af[2], bf[2];
            #pragma unroll
            for (int m2 = 0; m2 < 2; m2++) {
                int row = m2 * 16 + l16;
                int cc = (k0 >> 3) + ccb;
                af[m2] = *(const short8*)(As + (row * 64 + (cc ^ (row & 7))) * 8);
            }
            #pragma unroll
            for (int n2 = 0; n2 < 2; n2++) {
                int row = wave * 32 + n2 * 16 + l16;
                bf[n2] = *(const short8*)(Bs + (row * 16 + (ccb ^ (row & 15))) * 8);
            }
            #pragma unroll
            for (int m2 = 0; m2 < 2; m2++)
                #pragma unroll
                for (int n2 = 0; n2 < 2; n2++)
                    acc[m2][n2] = __builtin_amdgcn_mfma_f32_16x16x32_bf16(
                        af[m2], bf[n2], acc[m2][n2], 0, 0, 0);
        }
        __syncthreads();
    }
    #pragma unroll
    for (int m2 = 0; m2 < 2; m2++)
        #pragma unroll
        for (int n2 = 0; n2 < 2; n2++)
            #pragma unroll
            for (int reg = 0; reg < 4; reg++) {
                int m = m0 + m2 * 16 + quad * 4 + reg;
                int n = n0 + wave * 32 + n2 * 16 + l16;
                float v = acc[m2][n2][reg] + bias[n];
                if (mode == 1) {
                    v = 0.5f * v * (1.f + erff(v * 0.70710678118f));
                    outb[(size_t)m * N + n] = f2bf(v);
                } else {
                    outf[(size_t)m * N + n] = v;
                }
            }
}

// ---------------------------------------------------------------------------
// gemm_res (split-K): A[M][K] bf16, B[N][K] bf16, BK=128. Tile 32m x 64n.
__global__ __launch_bounds__(256) void gemm_res(
    const short* __restrict__ Ag, const short* __restrict__ Bw,
    const float* __restrict__ bias, const float* __restrict__ rsPtr,
    float* __restrict__ hm, int K, int Ks) {
    __shared__ short As[32 * 128];
    __shared__ short Bs[64 * 128];
    int tid = threadIdx.x;
    int m0 = blockIdx.y * 32, n0 = blockIdx.x * 64;
    int kbase = blockIdx.z * Ks;
    int wave = tid >> 6, lane = tid & 63, quad = lane >> 4, l16 = lane & 15;
    f32x4 acc[2];
    acc[0] = (f32x4){0.f, 0.f, 0.f, 0.f};
    acc[1] = (f32x4){0.f, 0.f, 0.f, 0.f};
    for (int k0 = kbase; k0 < kbase + Ks; k0 += 128) {
        #pragma unroll
        for (int e = 0; e < 2; e++) {
            int p = e * 256 + tid;
            int row = p >> 4, seg = (p & 15) ^ (row & 15);
            async16(Ag + (size_t)(m0 + row) * K + k0 + seg * 8, As + p * 8);
        }
        #pragma unroll
        for (int e = 0; e < 4; e++) {
            int p = e * 256 + tid;
            int row = p >> 4, seg = (p & 15) ^ (row & 15);
            async16(Bw + (size_t)(n0 + row) * K + k0 + seg * 8, Bs + p * 8);
        }
        __syncthreads();
        #pragma unroll
        for (int ksub = 0; ksub < 4; ksub++) {
            int ccb = ksub * 4 + quad;
            short8 bf;
            {
                int row = wave * 16 + l16;
                bf = *(const short8*)(Bs + (row * 16 + (ccb ^ (row & 15))) * 8);
            }
            #pragma unroll
            for (int m2 = 0; m2 < 2; m2++) {
                int row = m2 * 16 + l16;
                short8 af = *(const short8*)(As + (row * 16 + (ccb ^ (row & 15))) * 8);
                acc[m2] = __builtin_amdgcn_mfma_f32_16x16x32_bf16(af, bf, acc[m2], 0, 0, 0);
            }
        }
        __syncthreads();
    }
    float rsv = *rsPtr;
    bool addb = (blockIdx.z == 0);
    #pragma unroll
    for (int m2 = 0; m2 < 2; m2++)
        #pragma unroll
        for (int reg = 0; reg < 4; reg++) {
            int m = m0 + m2 * 16 + quad * 4 + reg;
            int n = n0 + wave * 16 + l16;
            float v = acc[m2][reg] + (addb ? bias[n] : 0.f);
            atomicAdd(&hm[(size_t)m * 512 + n], rsv * v);
        }
}

// ---------------------------------------------------------------------------
__global__ __launch_bounds__(256) void head_kernel(
    const float* __restrict__ h, const float* __restrict__ g,
    const float* __restrict__ bb, const float* __restrict__ w,
    const float* __restrict__ bias0, float* __restrict__ out) {
    __shared__ float red[8];
    int token = blockIdx.x, tid = threadIdx.x;
    float v0 = h[token * 512 + tid], v1 = h[token * 512 + tid + 256];
    float s  = block_reduce_sum_256(v0 + v1, red);
    float ss = block_reduce_sum_256(v0 * v0 + v1 * v1, red);
    float mu = s * (1.f / 512.f);
    float var = ss * (1.f / 512.f) - mu * mu;
    float inv = rsqrtf(var + EPS);
    float n0 = (v0 - mu) * inv * g[tid] + bb[tid];
    float n1 = (v1 - mu) * inv * g[tid + 256] + bb[tid + 256];
    float dot = block_reduce_sum_256(n0 * w[tid] + n1 * w[tid + 256], red);
    if (tid == 0) out[token] = dot + bias0[0];
}

// ---------------------------------------------------------------------------
extern "C" void kernel_launch(void* const* d_in, const int* in_sizes, int n_in,
                              void* d_out, int out_size, void* d_ws, size_t ws_size,
                              hipStream_t stream) {
    const float* x       = (const float*)d_in[0];
    const float* z       = (const float*)d_in[1];
    const float* conv_w  = (const float*)d_in[2];
    const float* conv_b  = (const float*)d_in[3];
    const float* tok_g   = (const float*)d_in[4];
    const float* tok_b   = (const float*)d_in[5];
    const float* film_w  = (const float*)d_in[6];
    const float* film_b  = (const float*)d_in[7];
    const float* ln1_g   = (const float*)d_in[8];
    const float* ln1_b   = (const float*)d_in[9];
    const float* kqv_w   = (const float*)d_in[10];
    const float* kqv_b   = (const float*)d_in[11];
    const float* proj_w  = (const float*)d_in[12];
    const float* proj_b  = (const float*)d_in[13];
    const float* ln2_g   = (const float*)d_in[14];
    const float* ln2_b   = (const float*)d_in[15];
    const float* mlp_w1  = (const float*)d_in[16];
    const float* mlp_b1  = (const float*)d_in[17];
    const float* mlp_w2  = (const float*)d_in[18];
    const float* mlp_b2  = (const float*)d_in[19];
    const float* rs_attn = (const float*)d_in[20];
    const float* rs_mlp  = (const float*)d_in[21];
    const float* head_g  = (const float*)d_in[22];
    const float* head_b  = (const float*)d_in[23];
    const float* head_w  = (const float*)d_in[24];
    const float* head_bs = (const float*)d_in[25];
    float* out = (float*)d_out;

    float* ws = (float*)d_ws;
    float* gb    = ws;                  // 524288 f
    float* h     = gb + 524288;         // 262144 f
    float* ropeS = h + 262144;          // 1024 f
    float* ropeC = ropeS + 1024;        // 1024 f
    short* sb = (short*)(ropeC + 1024);
    short* wbf   = sb;                 // 294912
    short* kqvT  = wbf   + 294912;     // 4718592
    short* projT = kqvT  + 4718592;    // 1572864
    short* mlp1T = projT + 1572864;    // 6291456
    short* mlp2T = mlp1T + 6291456;    // 6291456
    short* yvb   = mlp2T + 6291456;    // 262144
    short* mbuf  = yvb   + 262144;     // 1048576
    short* xbf   = mbuf  + 1048576;    // 6291456

    prep_all<<<23172, 256, 0, stream>>>(
        z, film_w, film_b, gb, conv_w, wbf, x, xbf, ropeS, ropeC,
        kqv_w, kqvT, proj_w, projT, mlp_w1, mlp1T, mlp_w2, mlp2T);

    conv_fused<<<512, 256, 0, stream>>>(xbf, wbf, conv_b, tok_g, tok_b, gb, h);

    for (int i = 0; i < 6; i++) {
        attn_fused<<<128, 256, 0, stream>>>(
            h, ln1_g + i * 512, ln1_b + i * 512,
            kqvT + (size_t)i * 1536 * 512, kqv_b + i * 1536, ropeS, ropeC, yvb);
        gemm_res<<<dim3(8, 16, 2), 256, 0, stream>>>(
            yvb, projT + (size_t)i * 512 * 512, proj_b + i * 512,
            rs_attn + i, h, 512, 256);
        gemm_ln<<<dim3(16, 16), 256, 0, stream>>>(
            h, ln2_g + i * 512, ln2_b + i * 512,
            mlp1T + (size_t)i * 2048 * 512, mlp_b1 + i * 2048,
            2048, 1, nullptr, mbuf);
        gemm_res<<<dim3(8, 16, 4), 256, 0, stream>>>(
            mbuf, mlp2T + (size_t)i * 512 * 2048, mlp_b2 + i * 512,
            rs_mlp + i, h, 2048, 512);
    }

    head_kernel<<<512, 256, 0, stream>>>(h, head_g, head_b, head_w, head_bs, out);
}

// Round 11
// 465.324 us; speedup vs baseline: 3.0645x; 1.0005x over previous
//
#include <hip/hip_runtime.h>
#include <math.h>

#define EPS 1e-5f

typedef __attribute__((ext_vector_type(8))) short short8;
typedef __attribute__((ext_vector_type(4))) float f32x4;

__device__ __forceinline__ short f2bf(float f) {
    unsigned u = __float_as_uint(f);
    u += 0x7fffu + ((u >> 16) & 1u);
    return (short)(u >> 16);
}
__device__ __forceinline__ float bf2f(short s) {
    return __uint_as_float(((unsigned)(unsigned short)s) << 16);
}
__device__ __forceinline__ void async16(const void* g, void* l) {
    __builtin_amdgcn_global_load_lds(
        (const __attribute__((address_space(1))) unsigned*)g,
        (__attribute__((address_space(3))) unsigned*)l, 16, 0, 0);
}

// ---------------------------------------------------------------------------
__device__ __forceinline__ float block_reduce_sum_256(float v, float* red) {
    #pragma unroll
    for (int o = 32; o > 0; o >>= 1) v += __shfl_down(v, o, 64);
    __syncthreads();
    if ((threadIdx.x & 63) == 0) red[threadIdx.x >> 6] = v;
    __syncthreads();
    return red[0] + red[1] + red[2] + red[3];
}

// ---------------------------------------------------------------------------
// prep_all: [0,512) film | [512,1664) conv_w cast | [1664,4736) x cast |
// [4736,4740) rope table | [4740,23172) weight transpose+cast (short8 stores).
__global__ __launch_bounds__(256) void prep_all(
    const float* __restrict__ z, const float* __restrict__ fw,
    const float* __restrict__ fb, float* __restrict__ gb,
    const float* __restrict__ conv_w, short* __restrict__ wbf,
    const float* __restrict__ x, short* __restrict__ xbf,
    float* __restrict__ ropeS, float* __restrict__ ropeC,
    const float* __restrict__ kqv_w, short* __restrict__ kqvT,
    const float* __restrict__ proj_w, short* __restrict__ projT,
    const float* __restrict__ mlp_w1, short* __restrict__ mlp1T,
    const float* __restrict__ mlp_w2, short* __restrict__ mlp2T) {
    int bi = blockIdx.x, tid = threadIdx.x;
    if (bi < 512) {
        __shared__ float zs[32];
        if (tid < 32) zs[tid] = z[bi * 32 + tid];
        __syncthreads();
        for (int j = tid; j < 1024; j += 256) {
            float acc = fb[j];
            #pragma unroll
            for (int k = 0; k < 32; k++) acc = fmaf(zs[k], fw[k * 1024 + j], acc);
            gb[bi * 1024 + j] = acc;
        }
        return;
    }
    if (bi < 1664) {
        int i = (bi - 512) * 256 + tid;
        wbf[i] = f2bf(conv_w[i]);
        return;
    }
    if (bi < 4736) {
        int i = (bi - 1664) * 256 + tid;
        float4 a = *(const float4*)(x + (size_t)i * 8);
        float4 b = *(const float4*)(x + (size_t)i * 8 + 4);
        short8 o = {f2bf(a.x), f2bf(a.y), f2bf(a.z), f2bf(a.w),
                    f2bf(b.x), f2bf(b.y), f2bf(b.z), f2bf(b.w)};
        *(short8*)(xbf + (size_t)i * 8) = o;
        return;
    }
    if (bi < 4740) {
        int idx = (bi - 4736) * 256 + tid;
        if (idx < 1024) {
            int t = idx >> 5, j = idx & 31;
            float ang = (float)t * expf(-(float)j * (logf(10000.f) / 32.f));
            ropeS[idx] = sinf(ang);
            ropeC[idx] = cosf(ang);
        }
        return;
    }
    __shared__ float tile[32][33];
    int rel0 = bi - 4740;
    const float* src; short* dst; int NT, K, N, rel;
    if (rel0 < 4608)       { src = kqv_w;  dst = kqvT;  NT = 48; K = 512;  N = 1536; rel = rel0; }
    else if (rel0 < 6144)  { src = proj_w; dst = projT; NT = 16; K = 512;  N = 512;  rel = rel0 - 4608; }
    else if (rel0 < 12288) { src = mlp_w1; dst = mlp1T; NT = 64; K = 512;  N = 2048; rel = rel0 - 6144; }
    else                   { src = mlp_w2; dst = mlp2T; NT = 16; K = 2048; N = 512;  rel = rel0 - 12288; }
    int per = NT * (K / 32);
    int layer = rel / per, r2 = rel - layer * per;
    int nt = r2 % NT, kt = r2 / NT;
    src += (size_t)layer * K * N;
    dst += (size_t)layer * N * K;
    int n0 = nt * 32, k0 = kt * 32;
    int lx = tid & 31, ly = tid >> 5;
    #pragma unroll
    for (int i = 0; i < 32; i += 8)
        tile[ly + i][lx] = src[(size_t)(k0 + ly + i) * N + n0 + lx];
    __syncthreads();
    // short8 (16B) stores: 32 rows x 4 chunks = 128 slots
    if (tid < 128) {
        int row = tid >> 2, c = tid & 3;
        short8 o;
        #pragma unroll
        for (int j = 0; j < 8; j++) o[j] = f2bf(tile[c * 8 + j][row]);
        *(short8*)(dst + (size_t)(n0 + row) * K + k0 + c * 8) = o;
    }
}

// ---------------------------------------------------------------------------
// conv_fused (R8 version): conv-as-GEMM + LN + FiLM + mean. 38.5 KB LDS.
__global__ __launch_bounds__(256, 2) void conv_fused(
    const short* __restrict__ xbf, const short* __restrict__ wbf,
    const float* __restrict__ cb, const float* __restrict__ tg,
    const float* __restrict__ tb, const float* __restrict__ gb,
    float* __restrict__ h) {
    __shared__ short As[64 * 32];
    __shared__ short Bs[512 * 32];
    __shared__ float redsum[4][64], redss[4][64];
    __shared__ float mu_s[64], inv_s[64];
    int bt = blockIdx.x, b = bt >> 5, t = bt & 31;
    int tid = threadIdx.x;
    int wave = tid >> 6, lane = tid & 63, quad = lane >> 4, l16 = lane & 15;

    int rowA = tid >> 2;
    int cA = (tid & 3) ^ ((rowA >> 1) & 3);
    int hn = rowA >> 3, wn2 = rowA & 7;
    long long baseA = (((long long)(b * 32 + t - 2) * 3) << 12)
                      + (long long)(hn * 8) * 64 + wn2 * 8;

    f32x4 acc[4][8];
    #pragma unroll
    for (int mt = 0; mt < 4; mt++)
        #pragma unroll
        for (int nt = 0; nt < 8; nt++) acc[mt][nt] = (f32x4){0.f, 0.f, 0.f, 0.f};

    for (int k0 = 0; k0 < 576; k0 += 32) {
        #pragma unroll
        for (int e = 0; e < 8; e++) {
            int s = e * 256 + tid;
            int n = s >> 2;
            int c = (s & 3) ^ ((n >> 1) & 3);
            async16(wbf + (size_t)n * 576 + k0 + c * 8, Bs + s * 8);
        }
        {
            int ks = (k0 >> 3) + cA;
            int ch = (ks >= 24) + (ks >= 48);
            int r = ks - ch * 24;
            int kt = r >> 3, ph = r & 7;
            short8 v8 = (short8){0, 0, 0, 0, 0, 0, 0, 0};
            if (t + kt >= 2)
                v8 = *(const short8*)(xbf + baseA
                        + ((long long)(kt * 3 + ch) << 12) + ph * 64);
            *(short8*)(As + tid * 8) = v8;
        }
        __syncthreads();
        short8 af[4], bf[8];
        #pragma unroll
        for (int mt = 0; mt < 4; mt++) {
            int row = mt * 16 + l16;
            int pc = quad ^ ((row >> 1) & 3);
            af[mt] = *(const short8*)(As + row * 32 + pc * 8);
        }
        #pragma unroll
        for (int nt = 0; nt < 8; nt++) {
            int row = wave * 128 + nt * 16 + l16;
            int pc = quad ^ ((row >> 1) & 3);
            bf[nt] = *(const short8*)(Bs + row * 32 + pc * 8);
        }
        #pragma unroll
        for (int mt = 0; mt < 4; mt++)
            #pragma unroll
            for (int nt = 0; nt < 8; nt++)
                acc[mt][nt] = __builtin_amdgcn_mfma_f32_16x16x32_bf16(
                    af[mt], bf[nt], acc[mt][nt], 0, 0, 0);
        __syncthreads();
    }

    float cbn[8], tgn[8], tbn[8], Gn[8], Ben[8];
    #pragma unroll
    for (int nt = 0; nt < 8; nt++) {
        int n = wave * 128 + nt * 16 + l16;
        cbn[nt] = cb[n]; tgn[nt] = tg[n]; tbn[nt] = tb[n];
        Gn[nt]  = 1.f + 0.5f * gb[bt * 1024 + n];
        Ben[nt] = 0.5f * gb[bt * 1024 + 512 + n];
    }
    #pragma unroll
    for (int mt = 0; mt < 4; mt++)
        #pragma unroll
        for (int reg = 0; reg < 4; reg++) {
            float s = 0.f, ss = 0.f;
            #pragma unroll
            for (int nt = 0; nt < 8; nt++) {
                float v = acc[mt][nt][reg] + cbn[nt];
                s += v; ss += v * v;
            }
            #pragma unroll
            for (int o = 1; o < 16; o <<= 1) {
                s  += __shfl_xor(s, o, 64);
                ss += __shfl_xor(ss, o, 64);
            }
            if (l16 == 0) {
                int m = mt * 16 + quad * 4 + reg;
                redsum[wave][m] = s; redss[wave][m] = ss;
            }
        }
    __syncthreads();
    if (tid < 64) {
        float S  = redsum[0][tid] + redsum[1][tid] + redsum[2][tid] + redsum[3][tid];
        float SS = redss[0][tid] + redss[1][tid] + redss[2][tid] + redss[3][tid];
        float mu = S * (1.f / 512.f);
        float var = SS * (1.f / 512.f) - mu * mu;
        mu_s[tid] = mu; inv_s[tid] = rsqrtf(var + EPS);
    }
    __syncthreads();
    float hacc[8] = {0.f, 0.f, 0.f, 0.f, 0.f, 0.f, 0.f, 0.f};
    #pragma unroll
    for (int mt = 0; mt < 4; mt++)
        #pragma unroll
        for (int reg = 0; reg < 4; reg++) {
            int m = mt * 16 + quad * 4 + reg;
            float mu = mu_s[m], inv = inv_s[m];
            #pragma unroll
            for (int nt = 0; nt < 8; nt++) {
                float v = acc[mt][nt][reg] + cbn[nt];
                hacc[nt] += (v - mu) * inv;
            }
        }
    #pragma unroll
    for (int nt = 0; nt < 8; nt++) {
        hacc[nt] += __shfl_xor(hacc[nt], 16, 64);
        hacc[nt] += __shfl_xor(hacc[nt], 32, 64);
    }
    if (quad == 0)
        #pragma unroll
        for (int nt = 0; nt < 8; nt++) {
            int n = wave * 128 + nt * 16 + l16;
            h[bt * 512 + n] = Gn[nt] * (tgn[nt] * (hacc[nt] * (1.f / 64.f)) + tbn[nt])
                              + Ben[nt];
        }
}

// ---------------------------------------------------------------------------
// attn_fused: LN -> kqv GEMM (BK=32, double-buffered B, 56 KB LDS) ->
// RoPE table -> MFMA QK^T -> parallel softmax -> MFMA PV -> yv bf16.
__global__ __launch_bounds__(256) void attn_fused(
    const float* __restrict__ hsrc, const float* __restrict__ lng,
    const float* __restrict__ lnb, const short* __restrict__ Bw,
    const float* __restrict__ bias, const float* __restrict__ ropeS,
    const float* __restrict__ ropeC, short* __restrict__ yv) {
    __shared__ char smem[57344] __attribute__((aligned(16)));
    __shared__ float mu_s[32], inv_s[32];
    short* As = (short*)smem;                      // 32 KB
    short* BsB[2] = {(short*)(smem + 32768), (short*)(smem + 45056)};  // 12 KB ea
    // attention phase overlays:
    float (*qsf)[64] = (float(*)[64])(smem);
    float (*ksf)[64] = (float(*)[64])(smem + 8192);
    short* vT  = (short*)(smem + 16384);
    short* qrb = (short*)(smem + 20480);
    short* krb = (short*)(smem + 24576);
    float (*att)[33] = (float(*)[33])(smem + 28672);
    short* pA  = (short*)(smem + 36864);
    int blk = blockIdx.x, b = blk >> 3, hh = blk & 7;
    int tid = threadIdx.x;
    int m0 = b * 32;
    // LN pass 1
    {
        int row = tid >> 3, l8 = tid & 7;
        const float* hp = hsrc + (size_t)(m0 + row) * 512 + l8 * 64;
        float s = 0.f, ss = 0.f;
        #pragma unroll
        for (int i = 0; i < 16; i++) {
            float4 v = *(const float4*)(hp + i * 4);
            s += v.x + v.y + v.z + v.w;
            ss += v.x * v.x + v.y * v.y + v.z * v.z + v.w * v.w;
        }
        s += __shfl_xor(s, 1, 64); ss += __shfl_xor(ss, 1, 64);
        s += __shfl_xor(s, 2, 64); ss += __shfl_xor(ss, 2, 64);
        s += __shfl_xor(s, 4, 64); ss += __shfl_xor(ss, 4, 64);
        if (l8 == 0) {
            float mu = s * (1.f / 512.f);
            float var = ss * (1.f / 512.f) - mu * mu;
            mu_s[row] = mu;
            inv_s[row] = rsqrtf(var + EPS);
        }
    }
    // early prefetch of B k0=0 (192 rows x 4 chunks = 768 slots, 3/thread)
    #pragma unroll
    for (int e = 0; e < 3; e++) {
        int p = e * 256 + tid;
        int row = p >> 2, seg = (p & 3) ^ ((row >> 1) & 3);
        int n = ((row >> 6) << 9) + hh * 64 + (row & 63);
        async16(Bw + (size_t)n * 512 + seg * 8, BsB[0] + p * 8);
    }
    __syncthreads();
    // LN pass 2 -> As (full K, swizzle over 64 chunks)
    #pragma unroll
    for (int e = 0; e < 8; e++) {
        int lc = e * 256 + tid;
        int row = lc >> 6, cc = lc & 63;
        float mu = mu_s[row], inv = inv_s[row];
        const float* hp = hsrc + (size_t)(m0 + row) * 512 + cc * 8;
        float4 a = *(const float4*)hp, b2 = *(const float4*)(hp + 4);
        float4 g0 = *(const float4*)(lng + cc * 8), g1 = *(const float4*)(lng + cc * 8 + 4);
        float4 b0 = *(const float4*)(lnb + cc * 8), b1 = *(const float4*)(lnb + cc * 8 + 4);
        short8 o = {f2bf((a.x - mu) * inv * g0.x + b0.x),
                    f2bf((a.y - mu) * inv * g0.y + b0.y),
                    f2bf((a.z - mu) * inv * g0.z + b0.z),
                    f2bf((a.w - mu) * inv * g0.w + b0.w),
                    f2bf((b2.x - mu) * inv * g1.x + b1.x),
                    f2bf((b2.y - mu) * inv * g1.y + b1.y),
                    f2bf((b2.z - mu) * inv * g1.z + b1.z),
                    f2bf((b2.w - mu) * inv * g1.w + b1.w)};
        *(short8*)(As + (row * 64 + (cc ^ (row & 7))) * 8) = o;
    }
    __syncthreads();
    int wave = tid >> 6, lane = tid & 63, quad = lane >> 4, l16 = lane & 15;
    f32x4 acc[2][3];
    #pragma unroll
    for (int m2 = 0; m2 < 2; m2++)
        #pragma unroll
        for (int g = 0; g < 3; g++) acc[m2][g] = (f32x4){0.f, 0.f, 0.f, 0.f};
    for (int it = 0; it < 16; it++) {
        short* Bsc = BsB[it & 1];
        if (it < 15) {
            int k0n = (it + 1) * 32;
            short* Bsn = BsB[(it + 1) & 1];
            #pragma unroll
            for (int e = 0; e < 3; e++) {
                int p = e * 256 + tid;
                int row = p >> 2, seg = (p & 3) ^ ((row >> 1) & 3);
                int n = ((row >> 6) << 9) + hh * 64 + (row & 63);
                async16(Bw + (size_t)n * 512 + k0n + seg * 8, Bsn + p * 8);
            }
        }
        int cc = it * 4 + quad;     // logical A-chunk for this k-step
        short8 af[2], bf[3];
        #pragma unroll
        for (int m2 = 0; m2 < 2; m2++) {
            int row = m2 * 16 + l16;
            af[m2] = *(const short8*)(As + (row * 64 + (cc ^ (row & 7))) * 8);
        }
        #pragma unroll
        for (int g = 0; g < 3; g++) {
            int row = g * 64 + wave * 16 + l16;
            int pc = quad ^ ((row >> 1) & 3);
            bf[g] = *(const short8*)(Bsc + (row * 4 + pc) * 8);
        }
        #pragma unroll
        for (int m2 = 0; m2 < 2; m2++)
            #pragma unroll
            for (int g = 0; g < 3; g++)
                acc[m2][g] = __builtin_amdgcn_mfma_f32_16x16x32_bf16(
                    af[m2], bf[g], acc[m2][g], 0, 0, 0);
        __syncthreads();
    }
    // epilogue: k,q fp32 -> LDS; v -> vT bf16
    float bb0 = bias[hh * 64 + wave * 16 + l16];
    float bb1 = bias[512 + hh * 64 + wave * 16 + l16];
    float bb2 = bias[1024 + hh * 64 + wave * 16 + l16];
    int dcol = wave * 16 + l16;
    #pragma unroll
    for (int m2 = 0; m2 < 2; m2++)
        #pragma unroll
        for (int reg = 0; reg < 4; reg++) {
            int tkn = m2 * 16 + quad * 4 + reg;
            ksf[tkn][dcol] = acc[m2][0][reg] + bb0;
            qsf[tkn][dcol] = acc[m2][1][reg] + bb1;
            vT[dcol * 32 + (((tkn >> 3) ^ (dcol & 3)) << 3) + (tkn & 7)]
                = f2bf(acc[m2][2][reg] + bb2);
        }
    __syncthreads();
    // RoPE (table)
    #pragma unroll
    for (int e = 0; e < 8; e++) {
        int idx = e * 256 + tid;
        int t = idx >> 6, d = idx & 63, j = d & 31;
        float sv = ropeS[t * 32 + j], cv = ropeC[t * 32 + j];
        float qv = qsf[t][d], kv = ksf[t][d];
        float qo = qsf[t][d ^ 32], ko = ksf[t][d ^ 32];
        float rq = (d < 32) ? -qo : qo;
        float rk = (d < 32) ? -ko : ko;
        int addr = t * 64 + (((d >> 3) ^ (t & 7)) << 3) + (d & 7);
        qrb[addr] = f2bf(qv * cv + rq * sv);
        krb[addr] = f2bf(kv * cv + rk * sv);
    }
    __syncthreads();
    int mw = wave & 1, nw = wave >> 1;
    // QK^T via MFMA
    {
        f32x4 sc = (f32x4){0.f, 0.f, 0.f, 0.f};
        #pragma unroll
        for (int kc = 0; kc < 2; kc++) {
            int rq = mw * 16 + l16;
            int rk = nw * 16 + l16;
            short8 aq = *(const short8*)(qrb + rq * 64 + ((((kc << 2) + quad) ^ (rq & 7)) << 3));
            short8 bk = *(const short8*)(krb + rk * 64 + ((((kc << 2) + quad) ^ (rk & 7)) << 3));
            sc = __builtin_amdgcn_mfma_f32_16x16x32_bf16(aq, bk, sc, 0, 0, 0);
        }
        #pragma unroll
        for (int reg = 0; reg < 4; reg++) {
            int qt = mw * 16 + quad * 4 + reg;
            int kt = nw * 16 + l16;
            att[qt][kt] = (kt > qt) ? -1e30f : sc[reg] * 0.125f;
        }
    }
    __syncthreads();
    // softmax: 8 lanes per row, 4 cols each
    {
        int row = tid >> 3, g = tid & 7;
        float v0 = att[row][g * 4], v1 = att[row][g * 4 + 1];
        float v2 = att[row][g * 4 + 2], v3 = att[row][g * 4 + 3];
        float mx = fmaxf(fmaxf(v0, v1), fmaxf(v2, v3));
        mx = fmaxf(mx, __shfl_xor(mx, 1, 64));
        mx = fmaxf(mx, __shfl_xor(mx, 2, 64));
        mx = fmaxf(mx, __shfl_xor(mx, 4, 64));
        float e0 = expf(v0 - mx), e1 = expf(v1 - mx);
        float e2 = expf(v2 - mx), e3 = expf(v3 - mx);
        float s = e0 + e1 + e2 + e3;
        s += __shfl_xor(s, 1, 64);
        s += __shfl_xor(s, 2, 64);
        s += __shfl_xor(s, 4, 64);
        float inv = 1.f / s;
        short* pp = pA + row * 32 + g * 4;
        pp[0] = f2bf(e0 * inv); pp[1] = f2bf(e1 * inv);
        pp[2] = f2bf(e2 * inv); pp[3] = f2bf(e3 * inv);
    }
    __syncthreads();
    // PV via MFMA
    {
        int rp = mw * 16 + l16;
        short8 ap = *(const short8*)(pA + rp * 32 + quad * 8);
        #pragma unroll
        for (int i = 0; i < 2; i++) {
            int nt = (wave >> 1) * 2 + i;
            int rv = nt * 16 + l16;
            short8 bv = *(const short8*)(vT + rv * 32 + (((quad ^ (rv & 3))) << 3));
            f32x4 o = (f32x4){0.f, 0.f, 0.f, 0.f};
            o = __builtin_amdgcn_mfma_f32_16x16x32_bf16(ap, bv, o, 0, 0, 0);
            #pragma unroll
            for (int reg = 0; reg < 4; reg++) {
                int t = mw * 16 + quad * 4 + reg;
                int d = nt * 16 + l16;
                yv[(size_t)(b * 32 + t) * 512 + hh * 64 + d] = f2bf(o[reg]);
            }
        }
    }
}

// ---------------------------------------------------------------------------
// gemm_ln (R8 version): LN-fused A, single-buffered B. 64.25 KB LDS.
__global__ __launch_bounds__(256) void gemm_ln(
    const float* __restrict__ hsrc, const float* __restrict__ lng,
    const float* __restrict__ lnb, const short* __restrict__ Bw,
    const float* __restrict__ bias, int N, int mode,
    float* __restrict__ outf, short* __restrict__ outb) {
    __shared__ short As[32 * 512];
    __shared__ short Bs[128 * 128];
    __shared__ float mu_s[32], inv_s[32];
    int tid = threadIdx.x;
    int m0 = blockIdx.y * 32, n0 = blockIdx.x * 128;
    {
        int row = tid >> 3, l8 = tid & 7;
        const float* hp = hsrc + (size_t)(m0 + row) * 512 + l8 * 64;
        float s = 0.f, ss = 0.f;
        #pragma unroll
        for (int i = 0; i < 16; i++) {
            float4 v = *(const float4*)(hp + i * 4);
            s += v.x + v.y + v.z + v.w;
            ss += v.x * v.x + v.y * v.y + v.z * v.z + v.w * v.w;
        }
        s += __shfl_xor(s, 1, 64); ss += __shfl_xor(ss, 1, 64);
        s += __shfl_xor(s, 2, 64); ss += __shfl_xor(ss, 2, 64);
        s += __shfl_xor(s, 4, 64); ss += __shfl_xor(ss, 4, 64);
        if (l8 == 0) {
            float mu = s * (1.f / 512.f);
            float var = ss * (1.f / 512.f) - mu * mu;
            mu_s[row] = mu;
            inv_s[row] = rsqrtf(var + EPS);
        }
    }
    // prefetch B k0=0 overlapping LN pass 2
    #pragma unroll
    for (int e = 0; e < 8; e++) {
        int p = e * 256 + tid;
        int row = p >> 4, seg = (p & 15) ^ (row & 15);
        async16(Bw + (size_t)(n0 + row) * 512 + seg * 8, Bs + p * 8);
    }
    __syncthreads();
    #pragma unroll
    for (int e = 0; e < 8; e++) {
        int lc = e * 256 + tid;
        int row = lc >> 6, cc = lc & 63;
        float mu = mu_s[row], inv = inv_s[row];
        const float* hp = hsrc + (size_t)(m0 + row) * 512 + cc * 8;
        float4 a = *(const float4*)hp, b = *(const float4*)(hp + 4);
        float4 g0 = *(const float4*)(lng + cc * 8), g1 = *(const float4*)(lng + cc * 8 + 4);
        float4 b0 = *(const float4*)(lnb + cc * 8), b1 = *(const float4*)(lnb + cc * 8 + 4);
        short8 o = {f2bf((a.x - mu) * inv * g0.x + b0.x),
                    f2bf((a.y - mu) * inv * g0.y + b0.y),
                    f2bf((a.z - mu) * inv * g0.z + b0.z),
                    f2bf((a.w - mu) * inv * g0.w + b0.w),
                    f2bf((b.x - mu) * inv * g1.x + b1.x),
                    f2bf((b.y - mu) * inv * g1.y + b1.y),
                    f2bf((b.z - mu) * inv * g1.z + b1.z),
                    f2bf((b.w - mu) * inv * g1.w + b1.w)};
        *(short8*)(As + (row * 64 + (cc ^ (row & 7))) * 8) = o;
    }
    __syncthreads();
    int wave = tid >> 6, lane = tid & 63, quad = lane >> 4, l16 = lane & 15;
    f32x4 acc[2][2];
    #pragma unroll
    for (int a2 = 0; a2 < 2; a2++)
        #pragma unroll
        for (int b2 = 0; b2 < 2; b2++) acc[a2][b2] = (f32x4){0.f, 0.f, 0.f, 0.f};
    for (int it = 0; it < 4; it++) {
        int k0 = it * 128;
        #pragma unroll
        for (int ksub = 0; ksub < 4; ksub++) {
            int ccb = ksub * 4 + quad;
            short8 af[2], bf[2];
            #pragma unroll
            for (int m2 = 0; m2 < 2; m2++) {
                int row = m2 * 16 + l16;
                int cc = (k0 >> 3) + ccb;
                af[m2] = *(const short8*)(As + (row * 64 + (cc ^ (row & 7))) * 8);
            }
            #pragma unroll
            for (int n2 = 0; n2 < 2; n2++) {
                int row = wave * 32 + n2 * 16 + l16;
                bf[n2] = *(const short8*)(Bs + (row * 16 + (ccb ^ (row & 15))) * 8);
            }
            #pragma unroll
            for (int m2 = 0; m2 < 2; m2++)
                #pragma unroll
                for (int n2 = 0; n2 < 2; n2++)
                    acc[m2][n2] = __builtin_amdgcn_mfma_f32_16x16x32_bf16(
                        af[m2], bf[n2], acc[m2][n2], 0, 0, 0);
        }
        __syncthreads();
        if (it < 3) {
            int k0n = (it + 1) * 128;
            #pragma unroll
            for (int e = 0; e < 8; e++) {
                int p = e * 256 + tid;
                int row = p >> 4, seg = (p & 15) ^ (row & 15);
                async16(Bw + (size_t)(n0 + row) * 512 + k0n + seg * 8, Bs + p * 8);
            }
            __syncthreads();
        }
    }
    #pragma unroll
    for (int m2 = 0; m2 < 2; m2++)
        #pragma unroll
        for (int n2 = 0; n2 < 2; n2++)
            #pragma unroll
            for (int reg = 0; reg < 4; reg++) {
                int m = m0 + m2 * 16 + quad * 4 + reg;
                int n = n0 + wave * 32 + n2 * 16 + l16;
                float v = acc[m2][n2][reg] + bias[n];
                if (mode == 1) {
                    v = 0.5f * v * (1.f + erff(v * 0.70710678118f));
                    outb[(size_t)m * N + n] = f2bf(v);
                } else {
                    outf[(size_t)m * N + n] = v;
                }
            }
}

// ---------------------------------------------------------------------------
// gemm_res (split-K, double-buffered, 48 KB LDS): tile 32m x 64n, BK=128.
__global__ __launch_bounds__(256) void gemm_res(
    const short* __restrict__ Ag, const short* __restrict__ Bw,
    const float* __restrict__ bias, const float* __restrict__ rsPtr,
    float* __restrict__ hm, int K, int Ks) {
    __shared__ short As[2][32 * 128];
    __shared__ short Bs[2][64 * 128];
    int tid = threadIdx.x;
    int m0 = blockIdx.y * 32, n0 = blockIdx.x * 64;
    int kbase = blockIdx.z * Ks;
    int wave = tid >> 6, lane = tid & 63, quad = lane >> 4, l16 = lane & 15;
    int nIter = Ks >> 7;
    f32x4 acc[2];
    acc[0] = (f32x4){0.f, 0.f, 0.f, 0.f};
    acc[1] = (f32x4){0.f, 0.f, 0.f, 0.f};
    auto stage = [&](int k0, int buf) {
        #pragma unroll
        for (int e = 0; e < 2; e++) {
            int p = e * 256 + tid;
            int row = p >> 4, seg = (p & 15) ^ (row & 15);
            async16(Ag + (size_t)(m0 + row) * K + k0 + seg * 8, As[buf] + p * 8);
        }
        #pragma unroll
        for (int e = 0; e < 4; e++) {
            int p = e * 256 + tid;
            int row = p >> 4, seg = (p & 15) ^ (row & 15);
            async16(Bw + (size_t)(n0 + row) * K + k0 + seg * 8, Bs[buf] + p * 8);
        }
    };
    stage(kbase, 0);
    __syncthreads();
    for (int it = 0; it < nIter; it++) {
        int cur = it & 1;
        if (it + 1 < nIter) stage(kbase + (it + 1) * 128, cur ^ 1);
        #pragma unroll
        for (int ksub = 0; ksub < 4; ksub++) {
            int ccb = ksub * 4 + quad;
            short8 bf;
            {
                int row = wave * 16 + l16;
                bf = *(const short8*)(Bs[cur] + (row * 16 + (ccb ^ (row & 15))) * 8);
            }
            #pragma unroll
            for (int m2 = 0; m2 < 2; m2++) {
                int row = m2 * 16 + l16;
                short8 af = *(const short8*)(As[cur] + (row * 16 + (ccb ^ (row & 15))) * 8);
                acc[m2] = __builtin_amdgcn_mfma_f32_16x16x32_bf16(af, bf, acc[m2], 0, 0, 0);
            }
        }
        __syncthreads();
    }
    float rsv = *rsPtr;
    bool addb = (blockIdx.z == 0);
    #pragma unroll
    for (int m2 = 0; m2 < 2; m2++)
        #pragma unroll
        for (int reg = 0; reg < 4; reg++) {
            int m = m0 + m2 * 16 + quad * 4 + reg;
            int n = n0 + wave * 16 + l16;
            float v = acc[m2][reg] + (addb ? bias[n] : 0.f);
            atomicAdd(&hm[(size_t)m * 512 + n], rsv * v);
        }
}

// ---------------------------------------------------------------------------
__global__ __launch_bounds__(256) void head_kernel(
    const float* __restrict__ h, const float* __restrict__ g,
    const float* __restrict__ bb, const float* __restrict__ w,
    const float* __restrict__ bias0, float* __restrict__ out) {
    __shared__ float red[8];
    int token = blockIdx.x, tid = threadIdx.x;
    float v0 = h[token * 512 + tid], v1 = h[token * 512 + tid + 256];
    float s  = block_reduce_sum_256(v0 + v1, red);
    float ss = block_reduce_sum_256(v0 * v0 + v1 * v1, red);
    float mu = s * (1.f / 512.f);
    float var = ss * (1.f / 512.f) - mu * mu;
    float inv = rsqrtf(var + EPS);
    float n0 = (v0 - mu) * inv * g[tid] + bb[tid];
    float n1 = (v1 - mu) * inv * g[tid + 256] + bb[tid + 256];
    float dot = block_reduce_sum_256(n0 * w[tid] + n1 * w[tid + 256], red);
    if (tid == 0) out[token] = dot + bias0[0];
}

// ---------------------------------------------------------------------------
extern "C" void kernel_launch(void* const* d_in, const int* in_sizes, int n_in,
                              void* d_out, int out_size, void* d_ws, size_t ws_size,
                              hipStream_t stream) {
    const float* x       = (const float*)d_in[0];
    const float* z       = (const float*)d_in[1];
    const float* conv_w  = (const float*)d_in[2];
    const float* conv_b  = (const float*)d_in[3];
    const float* tok_g   = (const float*)d_in[4];
    const float* tok_b   = (const float*)d_in[5];
    const float* film_w  = (const float*)d_in[6];
    const float* film_b  = (const float*)d_in[7];
    const float* ln1_g   = (const float*)d_in[8];
    const float* ln1_b   = (const float*)d_in[9];
    const float* kqv_w   = (const float*)d_in[10];
    const float* kqv_b   = (const float*)d_in[11];
    const float* proj_w  = (const float*)d_in[12];
    const float* proj_b  = (const float*)d_in[13];
    const float* ln2_g   = (const float*)d_in[14];
    const float* ln2_b   = (const float*)d_in[15];
    const float* mlp_w1  = (const float*)d_in[16];
    const float* mlp_b1  = (const float*)d_in[17];
    const float* mlp_w2  = (const float*)d_in[18];
    const float* mlp_b2  = (const float*)d_in[19];
    const float* rs_attn = (const float*)d_in[20];
    const float* rs_mlp  = (const float*)d_in[21];
    const float* head_g  = (const float*)d_in[22];
    const float* head_b  = (const float*)d_in[23];
    const float* head_w  = (const float*)d_in[24];
    const float* head_bs = (const float*)d_in[25];
    float* out = (float*)d_out;

    float* ws = (float*)d_ws;
    float* gb    = ws;                  // 524288 f
    float* h     = gb + 524288;         // 262144 f
    float* ropeS = h + 262144;          // 1024 f
    float* ropeC = ropeS + 1024;        // 1024 f
    short* sb = (short*)(ropeC + 1024);
    short* wbf   = sb;                 // 294912
    short* kqvT  = wbf   + 294912;     // 4718592
    short* projT = kqvT  + 4718592;    // 1572864
    short* mlp1T = projT + 1572864;    // 6291456
    short* mlp2T = mlp1T + 6291456;    // 6291456
    short* yvb   = mlp2T + 6291456;    // 262144
    short* mbuf  = yvb   + 262144;     // 1048576
    short* xbf   = mbuf  + 1048576;    // 6291456

    prep_all<<<23172, 256, 0, stream>>>(
        z, film_w, film_b, gb, conv_w, wbf, x, xbf, ropeS, ropeC,
        kqv_w, kqvT, proj_w, projT, mlp_w1, mlp1T, mlp_w2, mlp2T);

    conv_fused<<<512, 256, 0, stream>>>(xbf, wbf, conv_b, tok_g, tok_b, gb, h);

    for (int i = 0; i < 6; i++) {
        attn_fused<<<128, 256, 0, stream>>>(
            h, ln1_g + i * 512, ln1_b + i * 512,
            kqvT + (size_t)i * 1536 * 512, kqv_b + i * 1536, ropeS, ropeC, yvb);
        gemm_res<<<dim3(8, 16, 2), 256, 0, stream>>>(
            yvb, projT + (size_t)i * 512 * 512, proj_b + i * 512,
            rs_attn + i, h, 512, 256);
        gemm_ln<<<dim3(16, 16), 256, 0, stream>>>(
            h, ln2_g + i * 512, ln2_b + i * 512,
            mlp1T + (size_t)i * 2048 * 512, mlp_b1 + i * 2048,
            2048, 1, nullptr, mbuf);
        gemm_res<<<dim3(8, 16, 4), 256, 0, stream>>>(
            mbuf, mlp2T + (size_t)i * 512 * 2048, mlp_b2 + i * 512,
            rs_mlp + i, h, 2048, 512);
    }

    head_kernel<<<512, 256, 0, stream>>>(h, head_g, head_b, head_w, head_bs, out);
}